// Round 12
// baseline (5781.030 us; speedup 1.0000x reference)
//
#include <hip/hip_runtime.h>
#include <cmath>

#define B_ 256
#define T_ 256
#define F_ 40
#define H_ 256
#define A_ 64
#define HOR_ 60
#define DSP_ 192
#define ENC_NBLK 128
#define GRP_SZ 16     // blocks per enc barrier group (one dir x mtile)
#define WSTR 456      // LDS weight row stride in u16 (448 + pad)
#define FPAD 32       // counter stride in ints (128 B -> own cacheline)
#define ADLD 1024     // Ad32 row stride: ctx(512) | h_even(256) | h_odd(256)
#define CT 64         // eo t-rows cached in LDS per decoder block (waves 0-1)
#define RR 16         // eo t-rows pinned in REGISTERS per wave (waves 2-7)

typedef unsigned short u16;
typedef unsigned int u32;
typedef __attribute__((ext_vector_type(8))) short bf16x8;
typedef __attribute__((ext_vector_type(4))) float f32x4;
typedef __attribute__((ext_vector_type(8))) u32 u32x8;
typedef __attribute__((ext_vector_type(4))) u32 u32x4;

__device__ __forceinline__ float sigm(float x){ return 1.f/(1.f+expf(-x)); }

__device__ __forceinline__ u16 f2bf(float x){
  u32 u = __float_as_uint(x);
  u32 r = (u + 0x7FFFu + ((u>>16)&1u)) >> 16;
  return (u16)r;
}
__device__ __forceinline__ float bf2f(u16 h){ return __uint_as_float(((u32)h)<<16); }
__device__ __forceinline__ u32 packsplit(float x){
  u16 hi = f2bf(x);
  u16 lo = f2bf(x - bf2f(hi));
  return (u32)hi | ((u32)lo<<16);
}
__device__ __forceinline__ float unpack2f(u32 v){
  return __uint_as_float(v<<16) + __uint_as_float(v & 0xFFFF0000u);
}

__device__ __forceinline__ float wred_sum(float v){
  #pragma unroll
  for (int o=32;o>0;o>>=1) v += __shfl_xor(v,o);
  return v;
}
__device__ __forceinline__ float wred_max(float v){
  #pragma unroll
  for (int o=32;o>0;o>>=1) v = fmaxf(v,__shfl_xor(v,o));
  return v;
}

// PROVEN barrier primitive (r4/r8/r10, replay-stable): arrival = RELEASE
// fetch_add; wait = tid0 ACQUIRE-spin (every poll invalidates) + syncthreads.
__device__ __forceinline__ void cnt_signal(int* c){
  __hip_atomic_fetch_add(c, 1, __ATOMIC_RELEASE, __HIP_MEMORY_SCOPE_AGENT);
}
__device__ __forceinline__ void cnt_wait(const int* c, int n, int tid){
  if (tid == 0){
    while (__hip_atomic_load(c, __ATOMIC_ACQUIRE, __HIP_MEMORY_SCOPE_AGENT) < n)
      __builtin_amdgcn_s_sleep(1);
  }
  __syncthreads();
}

// ---- weight conversion: dst[n][k] (hi/lo bf16) = src[k][n], src = [Wx ; Wh] ----
__global__ void conv_w(const float* __restrict__ Wx, const float* __restrict__ Wh,
                       u16* __restrict__ hi, u16* __restrict__ lo,
                       int KX, int Ktot, int N){
  int idx = blockIdx.x*256 + threadIdx.x;
  if (idx >= N*Ktot) return;
  int n = idx / Ktot, k = idx - n*Ktot;
  float w = (k < KX) ? Wx[(size_t)k*N + n] : Wh[(size_t)(k-KX)*N + n];
  u16 h = f2bf(w);
  hi[idx] = h;
  lo[idx] = f2bf(w - bf2f(h));
}

// ---- spatial projection: hsp32[t][b][192] packed = x[b][t][:40] @ W_sp + b_sp ----
__global__ __launch_bounds__(192) void spatial_proj(
    const float* __restrict__ x, const float* __restrict__ W, const float* __restrict__ bsp,
    u32* __restrict__ hsp32){
  __shared__ float Ws[40][192];
  __shared__ float xr[40];
  int t = blockIdx.x, tid = threadIdx.x;
  for (int i = tid; i < 40*192; i += 192){ int k = i/192, c = i-k*192; Ws[k][c] = W[i]; }
  float bb = bsp[tid];
  __syncthreads();
  for (int b=0; b<B_; b++){
    if (tid < 40) xr[tid] = x[((size_t)b*T_ + t)*F_ + tid];
    __syncthreads();
    float acc = bb;
    #pragma unroll
    for (int k=0;k<40;k++) acc += xr[k]*Ws[k][tid];
    hsp32[((size_t)t*B_ + b)*DSP_ + tid] = packsplit(acc);
    __syncthreads();
  }
}

// ---- persistent bidirectional encoder scan (r8/r10 proven version, verbatim) ----
__global__ __launch_bounds__(256) void enc_scan(
    const u32* __restrict__ hsp32,
    const u16* __restrict__ W_hi, const u16* __restrict__ W_lo,
    const float* __restrict__ b_ef, const float* __restrict__ b_eb,
    u32* __restrict__ hbuf, u32* __restrict__ eo32, int* __restrict__ bar)
{
  extern __shared__ u16 smem[];
  u16* Whi = smem;                    // [4 gates][16 units][WSTR]
  u16* Wlo = smem + 4*16*WSTR;
  const int bid = blockIdx.x;
  const int grp = bid & 7;            // dir*4 + mtile
  const int nt  = bid >> 3;
  const int dir = grp >> 2;
  const int m0  = (grp & 3) * 64;
  const int u0  = nt * 16;
  const int tid = threadIdx.x;
  const int wave = tid >> 6, lane = tid & 63;
  const int lrow = lane & 15, kblk = lane >> 4;
  const int koff = kblk * 8;
  {
    const size_t wbase = ((size_t)dir*1024 + u0) * 448;
    for (int idx = tid; idx < 4*16*448; idx += 256){
      int g = idx / (16*448);
      int r = idx - g*(16*448);
      int j = r / 448;
      int k = r - j*448;
      size_t go = wbase + ((size_t)g*256 + j)*448 + k;
      Whi[(g*16 + j)*WSTR + k] = W_hi[go];
      Wlo[(g*16 + j)*WSTR + k] = W_lo[go];
    }
  }
  const float* bias = dir ? b_eb : b_ef;
  float bg4[4];
  #pragma unroll
  for (int g=0; g<4; g++) bg4[g] = bias[g*H_ + u0 + lrow];
  __syncthreads();

  const int mrow = m0 + wave*16;
  const int arow = mrow + lrow;
  u32* hP0 = hbuf + (size_t)dir*(B_*H_);
  u32* hP1 = hbuf + (size_t)(2+dir)*(B_*H_);
  int* gbar = bar + grp*T_;
  float c_reg[4] = {0.f,0.f,0.f,0.f};

  for (int s=0; s<T_; s++){
    const int t = dir ? (T_-1-s) : s;
    f32x4 acc[4] = {};
    // ---- x part (k 0..191): independent of h -> before barrier ----
    const u32* abase = hsp32 + ((size_t)t*B_ + arow)*DSP_;
    #pragma unroll
    for (int ks=0; ks<6; ks++){
      int kb = ks*32 + koff;
      u32x8 la = *(const u32x8*)(abase + kb);
      bf16x8 ah, al;
      #pragma unroll
      for (int j=0;j<8;j++){ ah[j]=(short)(la[j]&0xFFFFu); al[j]=(short)(la[j]>>16); }
      #pragma unroll
      for (int g=0; g<4; g++){
        bf16x8 bh = *(const bf16x8*)(Whi + (g*16+lrow)*WSTR + kb);
        bf16x8 bl = *(const bf16x8*)(Wlo + (g*16+lrow)*WSTR + kb);
        acc[g] = __builtin_amdgcn_mfma_f32_16x16x32_bf16(ah, bh, acc[g], 0,0,0);
        acc[g] = __builtin_amdgcn_mfma_f32_16x16x32_bf16(ah, bl, acc[g], 0,0,0);
        acc[g] = __builtin_amdgcn_mfma_f32_16x16x32_bf16(al, bh, acc[g], 0,0,0);
      }
    }
    // ---- wait for group's h(s-1) ----
    if (s > 0){
      if (tid == 0){
        while (__hip_atomic_load(&gbar[s-1], __ATOMIC_ACQUIRE, __HIP_MEMORY_SCOPE_AGENT) < GRP_SZ)
          __builtin_amdgcn_s_sleep(1);
      }
      __syncthreads();
    }
    const u32* hin = (s & 1) ? hP1 : hP0;
    u32* hout      = (s & 1) ? hP0 : hP1;
    // ---- h part (k 192..447) ----
    const u32* hbase = hin + (size_t)arow*H_;
    #pragma unroll
    for (int ks=0; ks<8; ks++){
      int kb = ks*32 + koff;
      u32x8 la = *(const u32x8*)(hbase + kb);
      bf16x8 ah, al;
      #pragma unroll
      for (int j=0;j<8;j++){ ah[j]=(short)(la[j]&0xFFFFu); al[j]=(short)(la[j]>>16); }
      #pragma unroll
      for (int g=0; g<4; g++){
        bf16x8 bh = *(const bf16x8*)(Whi + (g*16+lrow)*WSTR + 192 + kb);
        bf16x8 bl = *(const bf16x8*)(Wlo + (g*16+lrow)*WSTR + 192 + kb);
        acc[g] = __builtin_amdgcn_mfma_f32_16x16x32_bf16(ah, bh, acc[g], 0,0,0);
        acc[g] = __builtin_amdgcn_mfma_f32_16x16x32_bf16(ah, bl, acc[g], 0,0,0);
        acc[g] = __builtin_amdgcn_mfma_f32_16x16x32_bf16(al, bh, acc[g], 0,0,0);
      }
    }
    // ---- cell (c in registers), h/eo writes ----
    #pragma unroll
    for (int r=0; r<4; r++){
      int brow = mrow + kblk*4 + r;
      float gi = acc[0][r] + bg4[0];
      float gf = acc[1][r] + bg4[1];
      float gg = acc[2][r] + bg4[2];
      float go = acc[3][r] + bg4[3];
      float cn = sigm(gf)*c_reg[r] + sigm(gi)*tanhf(gg);
      float hn = sigm(go)*tanhf(cn);
      c_reg[r] = cn;
      u32 hp = packsplit(hn);
      hout[(size_t)brow*H_ + u0 + lrow] = hp;
      eo32[((size_t)brow*T_ + t)*512 + dir*H_ + u0 + lrow] = hp;  // normal store: seed L2/L3
    }
    if (s == T_-1) break;
    __syncthreads();
    if (tid == 0)
      __hip_atomic_fetch_add(&gbar[s], 1, __ATOMIC_RELEASE, __HIP_MEMORY_SCOPE_AGENT);
  }
}

// ---- persistent decoder: eo in LDS (waves 0-1) + REGISTERS (waves 2-7 x RR rows) ----
__global__ __launch_bounds__(512,2) void dec_scan(
    const u32* __restrict__ eo32,
    const u16* __restrict__ Wet_hi, const u16* __restrict__ Wet_lo,
    const float* __restrict__ W_ih, const float* __restrict__ b_ih,
    const float* __restrict__ W_ic, const float* __restrict__ b_ic,
    const float* __restrict__ x, float* __restrict__ ep,
    const float* __restrict__ Wd, const float* __restrict__ v,
    const float* __restrict__ Wo, const float* __restrict__ bo,
    const u16* __restrict__ W_hi, const u16* __restrict__ W_lo,
    const float* __restrict__ b_d, const float* __restrict__ Wx_d,
    float* __restrict__ hdp, float* __restrict__ cd,
    u32* __restrict__ Ad32, float* __restrict__ py,
    float* __restrict__ out, int* __restrict__ cntA, int* __restrict__ cntB)
{
  __shared__ float sh_h[256], sh_hwd[64], sh_v[64], sh_sc[256], sh_w[256];
  __shared__ float red8[8][64];
  __shared__ float sh_red[4], sh_red2[4];
  __shared__ float shun[8][256];       // redc (phase A, two-pass) / gl (phase B) overlay
  __shared__ float em_s[512];
  __shared__ u32 eoL[CT*512];          // eo t<64 cache (128 KB) — covers waves 0-1
  const int b = blockIdx.x, tid = threadIdx.x;
  const int wave = tid >> 6, lane = tid & 63;
  const int bx = b & 15, by = b >> 4;      // phase-B role
  const int cr = tid >> 4, cu = tid & 15;  // cell role (tid<256)
  float c_reg = 0.f;
  float bg0=0,bg1=0,bg2=0,bg3=0, w00=0,w01=0,w02=0,w03=0;
  if (tid < 256){
    int uu = bx*16 + cu;
    bg0 = b_d[uu];       bg1 = b_d[256+uu];
    bg2 = b_d[512+uu];   bg3 = b_d[768+uu];
    w00 = Wx_d[uu];      w01 = Wx_d[256+uu];
    w02 = Wx_d[512+uu];  w03 = Wx_d[768+uu];
  }
  // ================= prologue (block-local) =================
  {   // stage eo t<CT into LDS (coalesced u32x4)
    const u32* src = eo32 + (size_t)b*T_*512;
    for (int i = tid; i < CT*512/4; i += 512)
      ((u32x4*)eoL)[i] = *(const u32x4*)(src + (size_t)i*4);
  }
  {
    const int lrow = lane & 15, kblk = lane >> 4, koff = kblk*8;
    // ep rows: [256t x 64] = eo[b] @ We^T (split MFMA); 8 waves x 2 M-tiles
    #pragma unroll
    for (int mi=0; mi<2; mi++){
      int mt = wave*2 + mi;
      f32x4 acc[4] = {};
      for (int ks=0; ks<16; ks++){
        int kb = ks*32 + koff;
        u32x8 ld = *(const u32x8*)(eo32 + ((size_t)b*T_ + mt*16 + lrow)*512 + kb);
        bf16x8 ah, al;
        #pragma unroll
        for (int j=0;j<8;j++){ ah[j]=(short)(ld[j]&0xFFFFu); al[j]=(short)(ld[j]>>16); }
        #pragma unroll
        for (int nf=0; nf<4; nf++){
          bf16x8 bh = *(const bf16x8*)(Wet_hi + (size_t)(nf*16+lrow)*512 + kb);
          bf16x8 bl = *(const bf16x8*)(Wet_lo + (size_t)(nf*16+lrow)*512 + kb);
          acc[nf] = __builtin_amdgcn_mfma_f32_16x16x32_bf16(ah, bh, acc[nf], 0,0,0);
          acc[nf] = __builtin_amdgcn_mfma_f32_16x16x32_bf16(ah, bl, acc[nf], 0,0,0);
          acc[nf] = __builtin_amdgcn_mfma_f32_16x16x32_bf16(al, bh, acc[nf], 0,0,0);
        }
      }
      #pragma unroll
      for (int nf=0; nf<4; nf++)
        #pragma unroll
        for (int r=0; r<4; r++)
          ep[((size_t)b*T_ + mt*16 + kblk*4 + r)*64 + nf*16 + lrow] = acc[nf][r];
    }
  }
  {   // enc-mean of own row (two-pass via shun)
    float cacc[8] = {};
    const u32* eo = eo32 + (size_t)b*T_*512 + lane*8;
    #pragma unroll 8
    for (int tt=0; tt<32; tt++){
      int t = wave*32 + tt;
      u32x4 e0 = *(const u32x4*)(eo + (size_t)t*512);
      u32x4 e1 = *(const u32x4*)(eo + (size_t)t*512 + 4);
      #pragma unroll
      for (int j=0;j<4;j++){ cacc[j] += unpack2f(e0[j]); cacc[4+j] += unpack2f(e1[j]); }
    }
    if (lane < 32){
      #pragma unroll
      for (int j=0;j<8;j++) shun[wave][lane*8+j] = cacc[j];
    }
    __syncthreads();
    if (tid < 256){
      float s0=0.f;
      #pragma unroll
      for (int q=0;q<8;q++) s0 += shun[q][tid];
      em_s[tid] = s0*(1.f/T_);
    }
    __syncthreads();
    if (lane >= 32){
      #pragma unroll
      for (int j=0;j<8;j++) shun[wave][(lane-32)*8+j] = cacc[j];
    }
    __syncthreads();
    if (tid < 256){
      float s1=0.f;
      #pragma unroll
      for (int q=0;q<8;q++) s1 += shun[q][tid];
      em_s[256+tid] = s1*(1.f/T_);
    }
    __syncthreads();
  }
  if (tid < 256){  // dec_h / dec_c (GEMV + tanh)
    float ah = b_ih[tid], ac = b_ic[tid];
    for (int k=0;k<512;k++){
      float e = em_s[k];
      ah += e*W_ih[(size_t)k*256 + tid];
      ac += e*W_ic[(size_t)k*256 + tid];
    }
    float h0 = tanhf(ah), c0 = tanhf(ac);
    sh_h[tid] = h0;
    hdp[(size_t)b*H_ + tid] = h0;                       // parity 0
    Ad32[(size_t)b*ADLD + 512 + tid] = packsplit(h0);   // h slot 0
    cd[(size_t)b*H_ + tid] = c0;
  }
  if (tid == 0){
    size_t xb = ((size_t)b*T_ + 255)*F_;
    py[b] = (x[xb] + x[xb+2])*0.5f;
  }
  if (tid >= 448) sh_v[tid-448] = v[tid-448];
  // pin first RR rows of this wave's context slice in registers (waves 2-7)
  u32x8 eoR[RR];
  if (wave >= 2){
    const u32* srcR = eo32 + ((size_t)b*T_ + wave*32)*512 + lane*8;
    #pragma unroll
    for (int r=0;r<RR;r++) eoR[r] = *(const u32x8*)(srcR + (size_t)r*512);
  }
  __syncthreads();
  // ================= main loop =================
  for (int s=0; s<=HOR_; s++){
    if (s > 0){
      cnt_wait(cntB + (size_t)((s-1)*16 + by)*FPAD, 16, tid);
      if (tid < 256) sh_h[tid] = hdp[(size_t)(s&1)*B_*H_ + (size_t)b*H_ + tid];
      __syncthreads();
      if (tid < 256){                    // head: y_{s-1}, py
        float p = sh_h[tid] * Wo[tid];
        p = wred_sum(p);
        if ((tid & 63) == 0) sh_red[tid>>6] = p;
      }
      __syncthreads();
      if (tid == 0){
        float y = sh_red[0]+sh_red[1]+sh_red[2]+sh_red[3] + bo[0];
        out[b*HOR_ + (s-1)] = y;
        py[b] = y;
      }
    }
    if (s == HOR_) break;
    {   // hWd
      float ssum = 0.f;
      for (int j=wave*32; j<wave*32+32; j++) ssum += sh_h[j]*Wd[(size_t)j*A_ + lane];
      red8[wave][lane] = ssum;
      __syncthreads();
      if (tid < 64){
        float a = 0.f;
        #pragma unroll
        for (int q=0;q<8;q++) a += red8[q][tid];
        sh_hwd[tid] = a;
      }
    }
    __syncthreads();
    {   // scores: 2 lanes per t
      int t = tid >> 1, aa = tid & 1;
      const float4* ep4 = (const float4*)(ep + ((size_t)(b*T_+t))*A_ + aa*32);
      float partial = 0.f;
      #pragma unroll
      for (int q=0;q<8;q++){
        float4 e4 = ep4[q];
        int a0 = aa*32 + q*4;
        partial += tanhf(e4.x + sh_hwd[a0+0]) * sh_v[a0+0];
        partial += tanhf(e4.y + sh_hwd[a0+1]) * sh_v[a0+1];
        partial += tanhf(e4.z + sh_hwd[a0+2]) * sh_v[a0+2];
        partial += tanhf(e4.w + sh_hwd[a0+3]) * sh_v[a0+3];
      }
      partial += __shfl_xor(partial, 1);
      if (aa == 0) sh_sc[t] = partial;
    }
    __syncthreads();
    if (tid < 256){                      // softmax over T
      float sc = sh_sc[tid];
      float m = wred_max(sc);
      if ((tid&63)==0) sh_red[tid>>6] = m;
      __syncthreads();
      m = fmaxf(fmaxf(sh_red[0],sh_red[1]), fmaxf(sh_red[2],sh_red[3]));
      float e = expf(sc - m);
      float su = wred_sum(e);
      if ((tid&63)==0) sh_red2[tid>>6] = su;
      __syncthreads();
      su = (sh_red2[0]+sh_red2[1])+(sh_red2[2]+sh_red2[3]);
      sh_w[tid] = e / su;
    } else { __syncthreads(); __syncthreads(); }
    __syncthreads();
    {   // context: waves 0-1 from LDS; waves 2-7: RR rows from regs + rest global
      float cacc[8] = {};
      if (wave < 2){
        for (int tt=0; tt<32; ++tt){
          int t = wave*32 + tt;
          float wgt = sh_w[t];
          const u32* p = eoL + t*512 + lane*8;
          u32x4 e0 = *(const u32x4*)p;
          u32x4 e1 = *(const u32x4*)(p + 4);
          #pragma unroll
          for (int j=0;j<4;j++){
            cacc[j]   += wgt * unpack2f(e0[j]);
            cacc[4+j] += wgt * unpack2f(e1[j]);
          }
        }
      } else {
        #pragma unroll
        for (int r=0;r<RR;r++){
          float wgt = sh_w[wave*32 + r];
          #pragma unroll
          for (int j=0;j<8;j++) cacc[j] += wgt * unpack2f(eoR[r][j]);
        }
        const u32* eo = eo32 + (size_t)b*T_*512 + lane*8;
        #pragma unroll 4
        for (int t=wave*32+RR; t<wave*32+32; ++t){
          float wgt = sh_w[t];
          u32x4 e0 = *(const u32x4*)(eo + (size_t)t*512);
          u32x4 e1 = *(const u32x4*)(eo + (size_t)t*512 + 4);
          #pragma unroll
          for (int j=0;j<4;j++){
            cacc[j]   += wgt * unpack2f(e0[j]);
            cacc[4+j] += wgt * unpack2f(e1[j]);
          }
        }
      }
      // two-pass reduce via shun
      if (lane < 32){
        #pragma unroll
        for (int j=0;j<8;j++) shun[wave][lane*8+j] = cacc[j];
      }
      __syncthreads();
      if (tid < 256){
        float c0 = 0.f;
        #pragma unroll
        for (int q=0;q<8;q++) c0 += shun[q][tid];
        Ad32[(size_t)b*ADLD + tid] = packsplit(c0);
      }
      __syncthreads();
      if (lane >= 32){
        #pragma unroll
        for (int j=0;j<8;j++) shun[wave][(lane-32)*8+j] = cacc[j];
      }
      __syncthreads();
      if (tid < 256){
        float c1 = 0.f;
        #pragma unroll
        for (int q=0;q<8;q++) c1 += shun[q][tid];
        Ad32[(size_t)b*ADLD + 256 + tid] = packsplit(c1);
      }
    }
    __syncthreads();                     // drain ctx/py/out stores
    if (tid == 0)
      cnt_signal(cntA + (size_t)(s*16 + by)*FPAD);
    // ---- phase B: wait own tile's 16 row arrivals; 8-wave K-split GEMM; cell ----
    cnt_wait(cntA + (size_t)(s*16 + by)*FPAD, 16, tid);
    if (s == 0 && tid < 256)
      c_reg = cd[(size_t)(by*16 + cr)*H_ + bx*16 + cu];
    const int par = s & 1;
    {
      const int g = wave & 3, kh = wave >> 2;
      const int r16 = lane & 15, kb4 = lane >> 4;
      f32x4 acc = {0.f,0.f,0.f,0.f};
      const u32* ar = Ad32 + (size_t)(by*16 + r16)*ADLD;
      const u16* WH = W_hi + (size_t)(g*256 + bx*16 + r16)*768;
      const u16* WL = W_lo + (size_t)(g*256 + bx*16 + r16)*768;
      for (int ks=kh*12; ks<kh*12+12; ks++){
        int kb = ks*32 + kb4*8;
        int kp = (kb < 512) ? kb : (kb + (par<<8));   // parity slot for h
        u32x8 ld = *(const u32x8*)(ar + kp);
        bf16x8 ah, al;
        #pragma unroll
        for (int j=0;j<8;j++){ ah[j]=(short)(ld[j]&0xFFFFu); al[j]=(short)(ld[j]>>16); }
        bf16x8 bh = *(const bf16x8*)(WH + kb);
        bf16x8 bl = *(const bf16x8*)(WL + kb);
        acc = __builtin_amdgcn_mfma_f32_16x16x32_bf16(ah, bh, acc, 0,0,0);
        acc = __builtin_amdgcn_mfma_f32_16x16x32_bf16(ah, bl, acc, 0,0,0);
        acc = __builtin_amdgcn_mfma_f32_16x16x32_bf16(al, bh, acc, 0,0,0);
      }
      #pragma unroll
      for (int vv=0; vv<4; vv++) shun[wave][(kb4*4+vv)*16 + r16] = acc[vv];
    }
    __syncthreads();
    if (tid < 256){                      // cell: thread (cr,cu), c in register
      float pyr = py[by*16 + cr];
      float gi = shun[0][cr*16+cu] + shun[4][cr*16+cu] + bg0 + pyr*w00;
      float gf = shun[1][cr*16+cu] + shun[5][cr*16+cu] + bg1 + pyr*w01;
      float gg = shun[2][cr*16+cu] + shun[6][cr*16+cu] + bg2 + pyr*w02;
      float go = shun[3][cr*16+cu] + shun[7][cr*16+cu] + bg3 + pyr*w03;
      float cn = sigm(gf)*c_reg + sigm(gi)*tanhf(gg);
      float hn = sigm(go)*tanhf(cn);
      c_reg = cn;
      size_t ridx = (size_t)(by*16+cr)*H_ + bx*16+cu;
      hdp[(size_t)((s+1)&1)*B_*H_ + ridx] = hn;
      Ad32[(size_t)(by*16+cr)*ADLD + 512 + (((s+1)&1)<<8) + bx*16+cu] = packsplit(hn);
    }
    __syncthreads();                     // drain h stores
    if (tid == 0)
      cnt_signal(cntB + (size_t)(s*16 + by)*FPAD);
  }
}

extern "C" void kernel_launch(void* const* d_in, const int* in_sizes, int n_in,
                              void* d_out, int out_size, void* d_ws, size_t ws_size,
                              hipStream_t stream)
{
  const float* x    = (const float*)d_in[0];
  const float* W_sp = (const float*)d_in[1];
  const float* b_sp = (const float*)d_in[2];
  const float* Wx_ef= (const float*)d_in[3];
  const float* Wh_ef= (const float*)d_in[4];
  const float* b_ef = (const float*)d_in[5];
  const float* Wx_eb= (const float*)d_in[6];
  const float* Wh_eb= (const float*)d_in[7];
  const float* b_eb = (const float*)d_in[8];
  const float* We   = (const float*)d_in[9];
  const float* Wd   = (const float*)d_in[10];
  const float* v    = (const float*)d_in[11];
  const float* Wx_d = (const float*)d_in[12];
  const float* Wh_d = (const float*)d_in[13];
  const float* b_d  = (const float*)d_in[14];
  const float* W_ih = (const float*)d_in[15];
  const float* b_ih = (const float*)d_in[16];
  const float* W_ic = (const float*)d_in[17];
  const float* b_ic = (const float*)d_in[18];
  const float* Wo   = (const float*)d_in[19];
  const float* bo   = (const float*)d_in[20];
  float* out = (float*)d_out;

  char* base = (char*)d_ws;
  auto alloc = [&](size_t bytes)->char*{
    char* p = base; base += (bytes + 255) & ~(size_t)255; return p;
  };
  u16* Wenc_hi = (u16*)alloc((size_t)2*1024*448*2);
  u16* Wenc_lo = (u16*)alloc((size_t)2*1024*448*2);
  u16* Wdec_hi = (u16*)alloc((size_t)1024*768*2);
  u16* Wdec_lo = (u16*)alloc((size_t)1024*768*2);
  u16* Wet_hi  = (u16*)alloc((size_t)64*512*2);
  u16* Wet_lo  = (u16*)alloc((size_t)64*512*2);
  u32* hsp32   = (u32*)alloc((size_t)T_*B_*DSP_*4);
  u32* hbuf    = (u32*)alloc((size_t)2*2*B_*H_*4);   // [parity][dir][b][u]
  u32* eo32    = (u32*)alloc((size_t)B_*T_*512*4);
  float* ep    = (float*)alloc((size_t)B_*T_*64*4);
  float* cd    = (float*)alloc((size_t)B_*H_*4);
  float* hdp   = (float*)alloc((size_t)2*B_*H_*4);   // parity h (fp32)
  u32* Ad32    = (u32*)alloc((size_t)B_*ADLD*4);
  float* pyb   = (float*)alloc((size_t)B_*4);
  int* bar     = (int*)alloc((size_t)8*T_*4);        // enc counters (r8)
  int* cntA    = (int*)alloc((size_t)HOR_*16*FPAD*4);
  int* cntB    = (int*)alloc((size_t)HOR_*16*FPAD*4);
  if ((size_t)(base - (char*)d_ws) > ws_size) return;

  // one-time weight conversions
  conv_w<<<dim3(1792),256,0,stream>>>(Wx_ef, Wh_ef, Wenc_hi, Wenc_lo, DSP_, 448, 1024);
  conv_w<<<dim3(1792),256,0,stream>>>(Wx_eb, Wh_eb, Wenc_hi+458752, Wenc_lo+458752, DSP_, 448, 1024);
  conv_w<<<dim3(3072),256,0,stream>>>(Wx_d+1024, Wh_d, Wdec_hi, Wdec_lo, 512, 768, 1024);
  conv_w<<<dim3(128),256,0,stream>>>(We, We, Wet_hi, Wet_lo, 512, 512, 64);

  spatial_proj<<<dim3(256),192,0,stream>>>(x, W_sp, b_sp, hsp32);

  hipMemsetAsync(hbuf, 0, (size_t)2*B_*H_*4, stream);          // parity-0 h = 0
  hipMemsetAsync(bar, 0, (size_t)8*T_*4, stream);              // enc counters
  hipMemsetAsync(cntA, 0, (size_t)HOR_*16*FPAD*4, stream);     // dec counters
  hipMemsetAsync(cntB, 0, (size_t)HOR_*16*FPAD*4, stream);

  enc_scan<<<dim3(ENC_NBLK), dim3(256), 2*4*16*WSTR*2, stream>>>(
      hsp32, Wenc_hi, Wenc_lo, b_ef, b_eb, hbuf, eo32, bar);

  dec_scan<<<dim3(256),512,0,stream>>>(
      eo32, Wet_hi, Wet_lo, W_ih, b_ih, W_ic, b_ic, x, ep,
      Wd, v, Wo, bo, Wdec_hi, Wdec_lo, b_d, Wx_d,
      hdp, cd, Ad32, pyb, out, cntA, cntB);
}

// Round 13
// 5551.720 us; speedup vs baseline: 1.0413x; 1.0413x over previous
//
#include <hip/hip_runtime.h>
#include <cmath>

#define B_ 256
#define T_ 256
#define F_ 40
#define H_ 256
#define A_ 64
#define HOR_ 60
#define DSP_ 192
#define ENC_NBLK 128
#define GRP_SZ 16     // blocks per enc barrier group (one dir x mtile)
#define WSTR 456      // LDS weight row stride in u16 (448 + pad)
#define FPAD 32       // counter stride in ints (128 B -> own cacheline)
#define ADLD 1024     // Ad32 row stride: ctx(512) | h_even(256) | h_odd(256)
#define CT 56         // eo t-rows cached in LDS per decoder block

typedef unsigned short u16;
typedef unsigned int u32;
typedef __attribute__((ext_vector_type(8))) short bf16x8;
typedef __attribute__((ext_vector_type(4))) float f32x4;
typedef __attribute__((ext_vector_type(8))) u32 u32x8;
typedef __attribute__((ext_vector_type(4))) u32 u32x4;

__device__ __forceinline__ float sigm(float x){ return 1.f/(1.f+expf(-x)); }

__device__ __forceinline__ u16 f2bf(float x){
  u32 u = __float_as_uint(x);
  u32 r = (u + 0x7FFFu + ((u>>16)&1u)) >> 16;
  return (u16)r;
}
__device__ __forceinline__ float bf2f(u16 h){ return __uint_as_float(((u32)h)<<16); }
__device__ __forceinline__ u32 packsplit(float x){
  u16 hi = f2bf(x);
  u16 lo = f2bf(x - bf2f(hi));
  return (u32)hi | ((u32)lo<<16);
}
__device__ __forceinline__ float unpack2f(u32 v){
  return __uint_as_float(v<<16) + __uint_as_float(v & 0xFFFF0000u);
}

__device__ __forceinline__ float wred_sum(float v){
  #pragma unroll
  for (int o=32;o>0;o>>=1) v += __shfl_xor(v,o);
  return v;
}
__device__ __forceinline__ float wred_max(float v){
  #pragma unroll
  for (int o=32;o>0;o>>=1) v = fmaxf(v,__shfl_xor(v,o));
  return v;
}

// PROVEN barrier primitive (r4/r8/r10, replay-stable): arrival = RELEASE
// fetch_add; wait = tid0 ACQUIRE-spin (every poll invalidates) + syncthreads.
__device__ __forceinline__ void cnt_signal(int* c){
  __hip_atomic_fetch_add(c, 1, __ATOMIC_RELEASE, __HIP_MEMORY_SCOPE_AGENT);
}
__device__ __forceinline__ void cnt_wait(const int* c, int n, int tid){
  if (tid == 0){
    while (__hip_atomic_load(c, __ATOMIC_ACQUIRE, __HIP_MEMORY_SCOPE_AGENT) < n)
      __builtin_amdgcn_s_sleep(1);
  }
  __syncthreads();
}

// ---- weight conversion: dst[n][k] (hi/lo bf16) = src[k][n], src = [Wx ; Wh] ----
__global__ void conv_w(const float* __restrict__ Wx, const float* __restrict__ Wh,
                       u16* __restrict__ hi, u16* __restrict__ lo,
                       int KX, int Ktot, int N){
  int idx = blockIdx.x*256 + threadIdx.x;
  if (idx >= N*Ktot) return;
  int n = idx / Ktot, k = idx - n*Ktot;
  float w = (k < KX) ? Wx[(size_t)k*N + n] : Wh[(size_t)(k-KX)*N + n];
  u16 h = f2bf(w);
  hi[idx] = h;
  lo[idx] = f2bf(w - bf2f(h));
}

// ---- spatial projection: hsp32[t][b][192] packed = x[b][t][:40] @ W_sp + b_sp ----
__global__ __launch_bounds__(192) void spatial_proj(
    const float* __restrict__ x, const float* __restrict__ W, const float* __restrict__ bsp,
    u32* __restrict__ hsp32){
  __shared__ float Ws[40][192];
  __shared__ float xr[40];
  int t = blockIdx.x, tid = threadIdx.x;
  for (int i = tid; i < 40*192; i += 192){ int k = i/192, c = i-k*192; Ws[k][c] = W[i]; }
  float bb = bsp[tid];
  __syncthreads();
  for (int b=0; b<B_; b++){
    if (tid < 40) xr[tid] = x[((size_t)b*T_ + t)*F_ + tid];
    __syncthreads();
    float acc = bb;
    #pragma unroll
    for (int k=0;k<40;k++) acc += xr[k]*Ws[k][tid];
    hsp32[((size_t)t*B_ + b)*DSP_ + tid] = packsplit(acc);
    __syncthreads();
  }
}

// ---- persistent bidirectional encoder scan (r8/r10 proven version, verbatim) ----
__global__ __launch_bounds__(256) void enc_scan(
    const u32* __restrict__ hsp32,
    const u16* __restrict__ W_hi, const u16* __restrict__ W_lo,
    const float* __restrict__ b_ef, const float* __restrict__ b_eb,
    u32* __restrict__ hbuf, u32* __restrict__ eo32, int* __restrict__ bar)
{
  extern __shared__ u16 smem[];
  u16* Whi = smem;                    // [4 gates][16 units][WSTR]
  u16* Wlo = smem + 4*16*WSTR;
  const int bid = blockIdx.x;
  const int grp = bid & 7;            // dir*4 + mtile
  const int nt  = bid >> 3;
  const int dir = grp >> 2;
  const int m0  = (grp & 3) * 64;
  const int u0  = nt * 16;
  const int tid = threadIdx.x;
  const int wave = tid >> 6, lane = tid & 63;
  const int lrow = lane & 15, kblk = lane >> 4;
  const int koff = kblk * 8;
  {
    const size_t wbase = ((size_t)dir*1024 + u0) * 448;
    for (int idx = tid; idx < 4*16*448; idx += 256){
      int g = idx / (16*448);
      int r = idx - g*(16*448);
      int j = r / 448;
      int k = r - j*448;
      size_t go = wbase + ((size_t)g*256 + j)*448 + k;
      Whi[(g*16 + j)*WSTR + k] = W_hi[go];
      Wlo[(g*16 + j)*WSTR + k] = W_lo[go];
    }
  }
  const float* bias = dir ? b_eb : b_ef;
  float bg4[4];
  #pragma unroll
  for (int g=0; g<4; g++) bg4[g] = bias[g*H_ + u0 + lrow];
  __syncthreads();

  const int mrow = m0 + wave*16;
  const int arow = mrow + lrow;
  u32* hP0 = hbuf + (size_t)dir*(B_*H_);
  u32* hP1 = hbuf + (size_t)(2+dir)*(B_*H_);
  int* gbar = bar + grp*T_;
  float c_reg[4] = {0.f,0.f,0.f,0.f};

  for (int s=0; s<T_; s++){
    const int t = dir ? (T_-1-s) : s;
    f32x4 acc[4] = {};
    // ---- x part (k 0..191): independent of h -> before barrier ----
    const u32* abase = hsp32 + ((size_t)t*B_ + arow)*DSP_;
    #pragma unroll
    for (int ks=0; ks<6; ks++){
      int kb = ks*32 + koff;
      u32x8 la = *(const u32x8*)(abase + kb);
      bf16x8 ah, al;
      #pragma unroll
      for (int j=0;j<8;j++){ ah[j]=(short)(la[j]&0xFFFFu); al[j]=(short)(la[j]>>16); }
      #pragma unroll
      for (int g=0; g<4; g++){
        bf16x8 bh = *(const bf16x8*)(Whi + (g*16+lrow)*WSTR + kb);
        bf16x8 bl = *(const bf16x8*)(Wlo + (g*16+lrow)*WSTR + kb);
        acc[g] = __builtin_amdgcn_mfma_f32_16x16x32_bf16(ah, bh, acc[g], 0,0,0);
        acc[g] = __builtin_amdgcn_mfma_f32_16x16x32_bf16(ah, bl, acc[g], 0,0,0);
        acc[g] = __builtin_amdgcn_mfma_f32_16x16x32_bf16(al, bh, acc[g], 0,0,0);
      }
    }
    // ---- wait for group's h(s-1) ----
    if (s > 0){
      if (tid == 0){
        while (__hip_atomic_load(&gbar[s-1], __ATOMIC_ACQUIRE, __HIP_MEMORY_SCOPE_AGENT) < GRP_SZ)
          __builtin_amdgcn_s_sleep(1);
      }
      __syncthreads();
    }
    const u32* hin = (s & 1) ? hP1 : hP0;
    u32* hout      = (s & 1) ? hP0 : hP1;
    // ---- h part (k 192..447) ----
    const u32* hbase = hin + (size_t)arow*H_;
    #pragma unroll
    for (int ks=0; ks<8; ks++){
      int kb = ks*32 + koff;
      u32x8 la = *(const u32x8*)(hbase + kb);
      bf16x8 ah, al;
      #pragma unroll
      for (int j=0;j<8;j++){ ah[j]=(short)(la[j]&0xFFFFu); al[j]=(short)(la[j]>>16); }
      #pragma unroll
      for (int g=0; g<4; g++){
        bf16x8 bh = *(const bf16x8*)(Whi + (g*16+lrow)*WSTR + 192 + kb);
        bf16x8 bl = *(const bf16x8*)(Wlo + (g*16+lrow)*WSTR + 192 + kb);
        acc[g] = __builtin_amdgcn_mfma_f32_16x16x32_bf16(ah, bh, acc[g], 0,0,0);
        acc[g] = __builtin_amdgcn_mfma_f32_16x16x32_bf16(ah, bl, acc[g], 0,0,0);
        acc[g] = __builtin_amdgcn_mfma_f32_16x16x32_bf16(al, bh, acc[g], 0,0,0);
      }
    }
    // ---- cell (c in registers), h/eo writes ----
    #pragma unroll
    for (int r=0; r<4; r++){
      int brow = mrow + kblk*4 + r;
      float gi = acc[0][r] + bg4[0];
      float gf = acc[1][r] + bg4[1];
      float gg = acc[2][r] + bg4[2];
      float go = acc[3][r] + bg4[3];
      float cn = sigm(gf)*c_reg[r] + sigm(gi)*tanhf(gg);
      float hn = sigm(go)*tanhf(cn);
      c_reg[r] = cn;
      u32 hp = packsplit(hn);
      hout[(size_t)brow*H_ + u0 + lrow] = hp;
      eo32[((size_t)brow*T_ + t)*512 + dir*H_ + u0 + lrow] = hp;  // normal store: seed L2/L3
    }
    if (s == T_-1) break;
    __syncthreads();
    if (tid == 0)
      __hip_atomic_fetch_add(&gbar[s], 1, __ATOMIC_RELEASE, __HIP_MEMORY_SCOPE_AGENT);
  }
}

// ---- persistent decoder (r11 structure; XCD-aligned phase-B tiles) ----
// 256 blocks x 512 thr. Prologue: ep rows (MFMA), enc-mean, dec_h/dec_c, py,
// + stage eo t<CT into LDS. Loop: phase A attn (row b), phase B LSTM tile
// rows [16*(b>>4),+16) x units [16*bx,+16) where bx = ((b&7)<<1)|((b>>3)&1):
// blocks b≡x (mod 8) land on XCD x (round-robin), so each XCD serves only
// 2 weight tiles (392 KB, L2-resident) instead of 16 (3.1 MB thrash).
__global__ __launch_bounds__(512) void dec_scan(
    const u32* __restrict__ eo32,
    const u16* __restrict__ Wet_hi, const u16* __restrict__ Wet_lo,
    const float* __restrict__ W_ih, const float* __restrict__ b_ih,
    const float* __restrict__ W_ic, const float* __restrict__ b_ic,
    const float* __restrict__ x, float* __restrict__ ep,
    const float* __restrict__ Wd, const float* __restrict__ v,
    const float* __restrict__ Wo, const float* __restrict__ bo,
    const u16* __restrict__ W_hi, const u16* __restrict__ W_lo,
    const float* __restrict__ b_d, const float* __restrict__ Wx_d,
    float* __restrict__ hdp, float* __restrict__ cd,
    u32* __restrict__ Ad32, float* __restrict__ py,
    float* __restrict__ out, int* __restrict__ cntA, int* __restrict__ cntB)
{
  __shared__ float sh_h[256], sh_hwd[64], sh_v[64], sh_sc[256], sh_w[256];
  __shared__ float red8[8][64];
  __shared__ float sh_red[4], sh_red2[4];
  __shared__ float redc[8][512];
  __shared__ float gl[8][16][16];
  __shared__ float em_s[512];
  __shared__ u32 eoL[CT*512];          // eo t<CT cache (114 KB)
  const int b = blockIdx.x, tid = threadIdx.x;
  const int wave = tid >> 6, lane = tid & 63;
  const int bx = ((b & 7) << 1) | ((b >> 3) & 1);   // XCD-aligned unit tile
  const int by = b >> 4;                            // row-group
  const int cr = tid >> 4, cu = tid & 15;  // cell role (tid<256)
  float c_reg = 0.f;
  float bg0=0,bg1=0,bg2=0,bg3=0, w00=0,w01=0,w02=0,w03=0;
  if (tid < 256){
    int uu = bx*16 + cu;
    bg0 = b_d[uu];       bg1 = b_d[256+uu];
    bg2 = b_d[512+uu];   bg3 = b_d[768+uu];
    w00 = Wx_d[uu];      w01 = Wx_d[256+uu];
    w02 = Wx_d[512+uu];  w03 = Wx_d[768+uu];
  }
  // ================= prologue (block-local) =================
  {   // stage eo t<CT into LDS (coalesced u32x4)
    const u32* src = eo32 + (size_t)b*T_*512;
    for (int i = tid; i < CT*512/4; i += 512)
      ((u32x4*)eoL)[i] = *(const u32x4*)(src + (size_t)i*4);
  }
  {
    const int lrow = lane & 15, kblk = lane >> 4, koff = kblk*8;
    // ep rows: [256t x 64] = eo[b] @ We^T (split MFMA); 8 waves x 2 M-tiles
    #pragma unroll
    for (int mi=0; mi<2; mi++){
      int mt = wave*2 + mi;
      f32x4 acc[4] = {};
      for (int ks=0; ks<16; ks++){
        int kb = ks*32 + koff;
        u32x8 ld = *(const u32x8*)(eo32 + ((size_t)b*T_ + mt*16 + lrow)*512 + kb);
        bf16x8 ah, al;
        #pragma unroll
        for (int j=0;j<8;j++){ ah[j]=(short)(ld[j]&0xFFFFu); al[j]=(short)(ld[j]>>16); }
        #pragma unroll
        for (int nf=0; nf<4; nf++){
          bf16x8 bh = *(const bf16x8*)(Wet_hi + (size_t)(nf*16+lrow)*512 + kb);
          bf16x8 bl = *(const bf16x8*)(Wet_lo + (size_t)(nf*16+lrow)*512 + kb);
          acc[nf] = __builtin_amdgcn_mfma_f32_16x16x32_bf16(ah, bh, acc[nf], 0,0,0);
          acc[nf] = __builtin_amdgcn_mfma_f32_16x16x32_bf16(ah, bl, acc[nf], 0,0,0);
          acc[nf] = __builtin_amdgcn_mfma_f32_16x16x32_bf16(al, bh, acc[nf], 0,0,0);
        }
      }
      #pragma unroll
      for (int nf=0; nf<4; nf++)
        #pragma unroll
        for (int r=0; r<4; r++)
          ep[((size_t)b*T_ + mt*16 + kblk*4 + r)*64 + nf*16 + lrow] = acc[nf][r];
    }
  }
  {   // enc-mean of own row
    float cacc[8] = {};
    const u32* eo = eo32 + (size_t)b*T_*512 + lane*8;
    #pragma unroll 8
    for (int tt=0; tt<32; tt++){
      int t = wave*32 + tt;
      u32x4 e0 = *(const u32x4*)(eo + (size_t)t*512);
      u32x4 e1 = *(const u32x4*)(eo + (size_t)t*512 + 4);
      #pragma unroll
      for (int j=0;j<4;j++){ cacc[j] += unpack2f(e0[j]); cacc[4+j] += unpack2f(e1[j]); }
    }
    #pragma unroll
    for (int j=0;j<8;j++) redc[wave][lane*8+j] = cacc[j];
    __syncthreads();
    if (tid < 256){
      float s0=0.f, s1=0.f;
      #pragma unroll
      for (int q=0;q<8;q++){ s0 += redc[q][tid]; s1 += redc[q][256+tid]; }
      em_s[tid] = s0*(1.f/T_); em_s[256+tid] = s1*(1.f/T_);
    }
    __syncthreads();
  }
  if (tid < 256){  // dec_h / dec_c (GEMV + tanh)
    float ah = b_ih[tid], ac = b_ic[tid];
    for (int k=0;k<512;k++){
      float e = em_s[k];
      ah += e*W_ih[(size_t)k*256 + tid];
      ac += e*W_ic[(size_t)k*256 + tid];
    }
    float h0 = tanhf(ah), c0 = tanhf(ac);
    sh_h[tid] = h0;
    hdp[(size_t)b*H_ + tid] = h0;                       // parity 0
    Ad32[(size_t)b*ADLD + 512 + tid] = packsplit(h0);   // h slot 0
    cd[(size_t)b*H_ + tid] = c0;
  }
  if (tid == 0){
    size_t xb = ((size_t)b*T_ + 255)*F_;
    py[b] = (x[xb] + x[xb+2])*0.5f;
  }
  if (tid >= 448) sh_v[tid-448] = v[tid-448];
  __syncthreads();
  // ================= main loop =================
  for (int s=0; s<=HOR_; s++){
    if (s > 0){
      cnt_wait(cntB + (size_t)((s-1)*16 + by)*FPAD, 16, tid);
      if (tid < 256) sh_h[tid] = hdp[(size_t)(s&1)*B_*H_ + (size_t)b*H_ + tid];
      __syncthreads();
      if (tid < 256){                    // head: y_{s-1}, py
        float p = sh_h[tid] * Wo[tid];
        p = wred_sum(p);
        if ((tid & 63) == 0) sh_red[tid>>6] = p;
      }
      __syncthreads();
      if (tid == 0){
        float y = sh_red[0]+sh_red[1]+sh_red[2]+sh_red[3] + bo[0];
        out[b*HOR_ + (s-1)] = y;
        py[b] = y;
      }
    }
    if (s == HOR_) break;
    {   // hWd
      float ssum = 0.f;
      for (int j=wave*32; j<wave*32+32; j++) ssum += sh_h[j]*Wd[(size_t)j*A_ + lane];
      red8[wave][lane] = ssum;
      __syncthreads();
      if (tid < 64){
        float a = 0.f;
        #pragma unroll
        for (int q=0;q<8;q++) a += red8[q][tid];
        sh_hwd[tid] = a;
      }
    }
    __syncthreads();
    {   // scores: 2 lanes per t
      int t = tid >> 1, aa = tid & 1;
      const float4* ep4 = (const float4*)(ep + ((size_t)(b*T_+t))*A_ + aa*32);
      float partial = 0.f;
      #pragma unroll
      for (int q=0;q<8;q++){
        float4 e4 = ep4[q];
        int a0 = aa*32 + q*4;
        partial += tanhf(e4.x + sh_hwd[a0+0]) * sh_v[a0+0];
        partial += tanhf(e4.y + sh_hwd[a0+1]) * sh_v[a0+1];
        partial += tanhf(e4.z + sh_hwd[a0+2]) * sh_v[a0+2];
        partial += tanhf(e4.w + sh_hwd[a0+3]) * sh_v[a0+3];
      }
      partial += __shfl_xor(partial, 1);
      if (aa == 0) sh_sc[t] = partial;
    }
    __syncthreads();
    if (tid < 256){                      // softmax over T
      float sc = sh_sc[tid];
      float m = wred_max(sc);
      if ((tid&63)==0) sh_red[tid>>6] = m;
      __syncthreads();
      m = fmaxf(fmaxf(sh_red[0],sh_red[1]), fmaxf(sh_red[2],sh_red[3]));
      float e = expf(sc - m);
      float su = wred_sum(e);
      if ((tid&63)==0) sh_red2[tid>>6] = su;
      __syncthreads();
      su = (sh_red2[0]+sh_red2[1])+(sh_red2[2]+sh_red2[3]);
      sh_w[tid] = e / su;
    } else { __syncthreads(); __syncthreads(); }
    __syncthreads();
    {   // context: wave w owns t in [w*32,+32); t<CT from LDS, else global
      float cacc[8] = {};
      const int t0 = wave*32, t1 = t0 + 32;
      const int tL = (t1 < CT) ? t1 : CT;
      for (int t=t0; t<tL; ++t){
        float wgt = sh_w[t];
        const u32* p = eoL + t*512 + lane*8;
        u32x4 e0 = *(const u32x4*)p;
        u32x4 e1 = *(const u32x4*)(p + 4);
        #pragma unroll
        for (int j=0;j<4;j++){
          cacc[j]   += wgt * unpack2f(e0[j]);
          cacc[4+j] += wgt * unpack2f(e1[j]);
        }
      }
      const u32* eo = eo32 + (size_t)b*T_*512 + lane*8;
      const int tG = (t0 > CT) ? t0 : CT;
      #pragma unroll 8
      for (int t=tG; t<t1; ++t){
        float wgt = sh_w[t];
        u32x4 e0 = *(const u32x4*)(eo + (size_t)t*512);
        u32x4 e1 = *(const u32x4*)(eo + (size_t)t*512 + 4);
        #pragma unroll
        for (int j=0;j<4;j++){
          cacc[j]   += wgt * unpack2f(e0[j]);
          cacc[4+j] += wgt * unpack2f(e1[j]);
        }
      }
      #pragma unroll
      for (int j=0;j<8;j++) redc[wave][lane*8+j] = cacc[j];
    }
    __syncthreads();
    if (tid < 256){
      float c0 = 0.f, c1 = 0.f;
      #pragma unroll
      for (int q=0;q<8;q++){ c0 += redc[q][tid]; c1 += redc[q][256+tid]; }
      Ad32[(size_t)b*ADLD + tid]       = packsplit(c0);
      Ad32[(size_t)b*ADLD + 256 + tid] = packsplit(c1);
    }
    __syncthreads();                     // drain ctx/py/out stores
    if (tid == 0)
      cnt_signal(cntA + (size_t)(s*16 + by)*FPAD);
    // ---- phase B: wait own tile's 16 row arrivals; 8-wave K-split GEMM; cell ----
    cnt_wait(cntA + (size_t)(s*16 + by)*FPAD, 16, tid);
    if (s == 0 && tid < 256)
      c_reg = cd[(size_t)(by*16 + cr)*H_ + bx*16 + cu];
    const int par = s & 1;
    {
      const int g = wave & 3, kh = wave >> 2;
      const int r16 = lane & 15, kb4 = lane >> 4;
      f32x4 acc = {0.f,0.f,0.f,0.f};
      const u32* ar = Ad32 + (size_t)(by*16 + r16)*ADLD;
      const u16* WH = W_hi + (size_t)(g*256 + bx*16 + r16)*768;
      const u16* WL = W_lo + (size_t)(g*256 + bx*16 + r16)*768;
      for (int ks=kh*12; ks<kh*12+12; ks++){
        int kb = ks*32 + kb4*8;
        int kp = (kb < 512) ? kb : (kb + (par<<8));   // parity slot for h
        u32x8 ld = *(const u32x8*)(ar + kp);
        bf16x8 ah, al;
        #pragma unroll
        for (int j=0;j<8;j++){ ah[j]=(short)(ld[j]&0xFFFFu); al[j]=(short)(ld[j]>>16); }
        bf16x8 bh = *(const bf16x8*)(WH + kb);
        bf16x8 bl = *(const bf16x8*)(WL + kb);
        acc = __builtin_amdgcn_mfma_f32_16x16x32_bf16(ah, bh, acc, 0,0,0);
        acc = __builtin_amdgcn_mfma_f32_16x16x32_bf16(ah, bl, acc, 0,0,0);
        acc = __builtin_amdgcn_mfma_f32_16x16x32_bf16(al, bh, acc, 0,0,0);
      }
      #pragma unroll
      for (int vv=0; vv<4; vv++) gl[wave][kb4*4+vv][r16] = acc[vv];
    }
    __syncthreads();
    if (tid < 256){                      // cell: thread (cr,cu), c in register
      float pyr = py[by*16 + cr];
      float gi = gl[0][cr][cu] + gl[4][cr][cu] + bg0 + pyr*w00;
      float gf = gl[1][cr][cu] + gl[5][cr][cu] + bg1 + pyr*w01;
      float gg = gl[2][cr][cu] + gl[6][cr][cu] + bg2 + pyr*w02;
      float go = gl[3][cr][cu] + gl[7][cr][cu] + bg3 + pyr*w03;
      float cn = sigm(gf)*c_reg + sigm(gi)*tanhf(gg);
      float hn = sigm(go)*tanhf(cn);
      c_reg = cn;
      size_t ridx = (size_t)(by*16+cr)*H_ + bx*16+cu;
      hdp[(size_t)((s+1)&1)*B_*H_ + ridx] = hn;
      Ad32[(size_t)(by*16+cr)*ADLD + 512 + (((s+1)&1)<<8) + bx*16+cu] = packsplit(hn);
    }
    __syncthreads();                     // drain h stores
    if (tid == 0)
      cnt_signal(cntB + (size_t)(s*16 + by)*FPAD);
  }
}

extern "C" void kernel_launch(void* const* d_in, const int* in_sizes, int n_in,
                              void* d_out, int out_size, void* d_ws, size_t ws_size,
                              hipStream_t stream)
{
  const float* x    = (const float*)d_in[0];
  const float* W_sp = (const float*)d_in[1];
  const float* b_sp = (const float*)d_in[2];
  const float* Wx_ef= (const float*)d_in[3];
  const float* Wh_ef= (const float*)d_in[4];
  const float* b_ef = (const float*)d_in[5];
  const float* Wx_eb= (const float*)d_in[6];
  const float* Wh_eb= (const float*)d_in[7];
  const float* b_eb = (const float*)d_in[8];
  const float* We   = (const float*)d_in[9];
  const float* Wd   = (const float*)d_in[10];
  const float* v    = (const float*)d_in[11];
  const float* Wx_d = (const float*)d_in[12];
  const float* Wh_d = (const float*)d_in[13];
  const float* b_d  = (const float*)d_in[14];
  const float* W_ih = (const float*)d_in[15];
  const float* b_ih = (const float*)d_in[16];
  const float* W_ic = (const float*)d_in[17];
  const float* b_ic = (const float*)d_in[18];
  const float* Wo   = (const float*)d_in[19];
  const float* bo   = (const float*)d_in[20];
  float* out = (float*)d_out;

  char* base = (char*)d_ws;
  auto alloc = [&](size_t bytes)->char*{
    char* p = base; base += (bytes + 255) & ~(size_t)255; return p;
  };
  u16* Wenc_hi = (u16*)alloc((size_t)2*1024*448*2);
  u16* Wenc_lo = (u16*)alloc((size_t)2*1024*448*2);
  u16* Wdec_hi = (u16*)alloc((size_t)1024*768*2);
  u16* Wdec_lo = (u16*)alloc((size_t)1024*768*2);
  u16* Wet_hi  = (u16*)alloc((size_t)64*512*2);
  u16* Wet_lo  = (u16*)alloc((size_t)64*512*2);
  u32* hsp32   = (u32*)alloc((size_t)T_*B_*DSP_*4);
  u32* hbuf    = (u32*)alloc((size_t)2*2*B_*H_*4);   // [parity][dir][b][u]
  u32* eo32    = (u32*)alloc((size_t)B_*T_*512*4);
  float* ep    = (float*)alloc((size_t)B_*T_*64*4);
  float* cd    = (float*)alloc((size_t)B_*H_*4);
  float* hdp   = (float*)alloc((size_t)2*B_*H_*4);   // parity h (fp32)
  u32* Ad32    = (u32*)alloc((size_t)B_*ADLD*4);
  float* pyb   = (float*)alloc((size_t)B_*4);
  int* bar     = (int*)alloc((size_t)8*T_*4);        // enc counters (r8)
  int* cntA    = (int*)alloc((size_t)HOR_*16*FPAD*4);
  int* cntB    = (int*)alloc((size_t)HOR_*16*FPAD*4);
  if ((size_t)(base - (char*)d_ws) > ws_size) return;

  // one-time weight conversions
  conv_w<<<dim3(1792),256,0,stream>>>(Wx_ef, Wh_ef, Wenc_hi, Wenc_lo, DSP_, 448, 1024);
  conv_w<<<dim3(1792),256,0,stream>>>(Wx_eb, Wh_eb, Wenc_hi+458752, Wenc_lo+458752, DSP_, 448, 1024);
  conv_w<<<dim3(3072),256,0,stream>>>(Wx_d+1024, Wh_d, Wdec_hi, Wdec_lo, 512, 768, 1024);
  conv_w<<<dim3(128),256,0,stream>>>(We, We, Wet_hi, Wet_lo, 512, 512, 64);

  spatial_proj<<<dim3(256),192,0,stream>>>(x, W_sp, b_sp, hsp32);

  hipMemsetAsync(hbuf, 0, (size_t)2*B_*H_*4, stream);          // parity-0 h = 0
  hipMemsetAsync(bar, 0, (size_t)8*T_*4, stream);              // enc counters
  hipMemsetAsync(cntA, 0, (size_t)HOR_*16*FPAD*4, stream);     // dec counters
  hipMemsetAsync(cntB, 0, (size_t)HOR_*16*FPAD*4, stream);

  enc_scan<<<dim3(ENC_NBLK), dim3(256), 2*4*16*WSTR*2, stream>>>(
      hsp32, Wenc_hi, Wenc_lo, b_ef, b_eb, hbuf, eo32, bar);

  dec_scan<<<dim3(256),512,0,stream>>>(
      eo32, Wet_hi, Wet_lo, W_ih, b_ih, W_ic, b_ic, x, ep,
      Wd, v, Wo, bo, Wdec_hi, Wdec_lo, b_d, Wx_d,
      hdp, cd, Ad32, pyb, out, cntA, cntB);
}

// Round 15
// 5456.340 us; speedup vs baseline: 1.0595x; 1.0175x over previous
//
#include <hip/hip_runtime.h>
#include <cmath>

#define B_ 256
#define T_ 256
#define F_ 40
#define H_ 256
#define A_ 64
#define HOR_ 60
#define DSP_ 192
#define ENC_NBLK 128
#define GRP_SZ 16     // blocks per enc barrier group (one dir x mtile)
#define WSTR 456      // LDS weight row stride in u16 (448 + pad)
#define FPAD 32       // counter stride in ints (128 B -> own cacheline)
#define ADLD 1024     // Ad32 row stride: ctx(512) | h_even(256) | h_odd(256)
#define CT 56         // eo t-rows cached in LDS per decoder block

typedef unsigned short u16;
typedef unsigned int u32;
typedef __attribute__((ext_vector_type(8))) short bf16x8;
typedef __attribute__((ext_vector_type(4))) float f32x4;
typedef __attribute__((ext_vector_type(8))) u32 u32x8;
typedef __attribute__((ext_vector_type(4))) u32 u32x4;

__device__ __forceinline__ float sigm(float x){ return 1.f/(1.f+expf(-x)); }

__device__ __forceinline__ u16 f2bf(float x){
  u32 u = __float_as_uint(x);
  u32 r = (u + 0x7FFFu + ((u>>16)&1u)) >> 16;
  return (u16)r;
}
__device__ __forceinline__ float bf2f(u16 h){ return __uint_as_float(((u32)h)<<16); }
__device__ __forceinline__ u32 packsplit(float x){
  u16 hi = f2bf(x);
  u16 lo = f2bf(x - bf2f(hi));
  return (u32)hi | ((u32)lo<<16);
}
__device__ __forceinline__ float unpack2f(u32 v){
  return __uint_as_float(v<<16) + __uint_as_float(v & 0xFFFF0000u);
}

__device__ __forceinline__ float wred_sum(float v){
  #pragma unroll
  for (int o=32;o>0;o>>=1) v += __shfl_xor(v,o);
  return v;
}
__device__ __forceinline__ float wred_max(float v){
  #pragma unroll
  for (int o=32;o>0;o>>=1) v = fmaxf(v,__shfl_xor(v,o));
  return v;
}

// PROVEN barrier primitive (r4/r8/r10, replay-stable): arrival = RELEASE
// fetch_add; wait = tid0 ACQUIRE-spin + syncthreads. Polls are THROTTLED
// (s_sleep needs a constant immediate -> template parameter): each
// agent-acquire poll emits buffer_inv, so tight spins keep every XCD's L2
// cold and contend with the arrival RMWs on the counter line.
__device__ __forceinline__ void cnt_signal(int* c){
  __hip_atomic_fetch_add(c, 1, __ATOMIC_RELEASE, __HIP_MEMORY_SCOPE_AGENT);
}
template<int SLP>
__device__ __forceinline__ void cnt_wait(const int* c, int n, int tid){
  if (tid == 0){
    while (__hip_atomic_load(c, __ATOMIC_ACQUIRE, __HIP_MEMORY_SCOPE_AGENT) < n)
      __builtin_amdgcn_s_sleep(SLP);
  }
  __syncthreads();
}

// ---- weight conversion: dst[n][k] (hi/lo bf16) = src[k][n], src = [Wx ; Wh] ----
__global__ void conv_w(const float* __restrict__ Wx, const float* __restrict__ Wh,
                       u16* __restrict__ hi, u16* __restrict__ lo,
                       int KX, int Ktot, int N){
  int idx = blockIdx.x*256 + threadIdx.x;
  if (idx >= N*Ktot) return;
  int n = idx / Ktot, k = idx - n*Ktot;
  float w = (k < KX) ? Wx[(size_t)k*N + n] : Wh[(size_t)(k-KX)*N + n];
  u16 h = f2bf(w);
  hi[idx] = h;
  lo[idx] = f2bf(w - bf2f(h));
}

// ---- spatial projection: hsp32[t][b][192] packed = x[b][t][:40] @ W_sp + b_sp ----
__global__ __launch_bounds__(192) void spatial_proj(
    const float* __restrict__ x, const float* __restrict__ W, const float* __restrict__ bsp,
    u32* __restrict__ hsp32){
  __shared__ float Ws[40][192];
  __shared__ float xr[40];
  int t = blockIdx.x, tid = threadIdx.x;
  for (int i = tid; i < 40*192; i += 192){ int k = i/192, c = i-k*192; Ws[k][c] = W[i]; }
  float bb = bsp[tid];
  __syncthreads();
  for (int b=0; b<B_; b++){
    if (tid < 40) xr[tid] = x[((size_t)b*T_ + t)*F_ + tid];
    __syncthreads();
    float acc = bb;
    #pragma unroll
    for (int k=0;k<40;k++) acc += xr[k]*Ws[k][tid];
    hsp32[((size_t)t*B_ + b)*DSP_ + tid] = packsplit(acc);
    __syncthreads();
  }
}

// ---- persistent bidirectional encoder scan (r8 structure; throttled polls) ----
__global__ __launch_bounds__(256) void enc_scan(
    const u32* __restrict__ hsp32,
    const u16* __restrict__ W_hi, const u16* __restrict__ W_lo,
    const float* __restrict__ b_ef, const float* __restrict__ b_eb,
    u32* __restrict__ hbuf, u32* __restrict__ eo32, int* __restrict__ bar)
{
  extern __shared__ u16 smem[];
  u16* Whi = smem;                    // [4 gates][16 units][WSTR]
  u16* Wlo = smem + 4*16*WSTR;
  const int bid = blockIdx.x;
  const int grp = bid & 7;            // dir*4 + mtile
  const int nt  = bid >> 3;
  const int dir = grp >> 2;
  const int m0  = (grp & 3) * 64;
  const int u0  = nt * 16;
  const int tid = threadIdx.x;
  const int wave = tid >> 6, lane = tid & 63;
  const int lrow = lane & 15, kblk = lane >> 4;
  const int koff = kblk * 8;
  {
    const size_t wbase = ((size_t)dir*1024 + u0) * 448;
    for (int idx = tid; idx < 4*16*448; idx += 256){
      int g = idx / (16*448);
      int r = idx - g*(16*448);
      int j = r / 448;
      int k = r - j*448;
      size_t go = wbase + ((size_t)g*256 + j)*448 + k;
      Whi[(g*16 + j)*WSTR + k] = W_hi[go];
      Wlo[(g*16 + j)*WSTR + k] = W_lo[go];
    }
  }
  const float* bias = dir ? b_eb : b_ef;
  float bg4[4];
  #pragma unroll
  for (int g=0; g<4; g++) bg4[g] = bias[g*H_ + u0 + lrow];
  __syncthreads();

  const int mrow = m0 + wave*16;
  const int arow = mrow + lrow;
  u32* hP0 = hbuf + (size_t)dir*(B_*H_);
  u32* hP1 = hbuf + (size_t)(2+dir)*(B_*H_);
  int* gbar = bar + grp*T_;
  float c_reg[4] = {0.f,0.f,0.f,0.f};

  for (int s=0; s<T_; s++){
    const int t = dir ? (T_-1-s) : s;
    f32x4 acc[4] = {};
    // ---- x part (k 0..191): independent of h -> before barrier ----
    const u32* abase = hsp32 + ((size_t)t*B_ + arow)*DSP_;
    #pragma unroll
    for (int ks=0; ks<6; ks++){
      int kb = ks*32 + koff;
      u32x8 la = *(const u32x8*)(abase + kb);
      bf16x8 ah, al;
      #pragma unroll
      for (int j=0;j<8;j++){ ah[j]=(short)(la[j]&0xFFFFu); al[j]=(short)(la[j]>>16); }
      #pragma unroll
      for (int g=0; g<4; g++){
        bf16x8 bh = *(const bf16x8*)(Whi + (g*16+lrow)*WSTR + kb);
        bf16x8 bl = *(const bf16x8*)(Wlo + (g*16+lrow)*WSTR + kb);
        acc[g] = __builtin_amdgcn_mfma_f32_16x16x32_bf16(ah, bh, acc[g], 0,0,0);
        acc[g] = __builtin_amdgcn_mfma_f32_16x16x32_bf16(ah, bl, acc[g], 0,0,0);
        acc[g] = __builtin_amdgcn_mfma_f32_16x16x32_bf16(al, bh, acc[g], 0,0,0);
      }
    }
    // ---- wait for group's h(s-1): throttled acquire spin ----
    if (s > 0){
      if (tid == 0){
        while (__hip_atomic_load(&gbar[s-1], __ATOMIC_ACQUIRE, __HIP_MEMORY_SCOPE_AGENT) < GRP_SZ)
          __builtin_amdgcn_s_sleep(8);
      }
      __syncthreads();
    }
    const u32* hin = (s & 1) ? hP1 : hP0;
    u32* hout      = (s & 1) ? hP0 : hP1;
    // ---- h part (k 192..447) ----
    const u32* hbase = hin + (size_t)arow*H_;
    #pragma unroll
    for (int ks=0; ks<8; ks++){
      int kb = ks*32 + koff;
      u32x8 la = *(const u32x8*)(hbase + kb);
      bf16x8 ah, al;
      #pragma unroll
      for (int j=0;j<8;j++){ ah[j]=(short)(la[j]&0xFFFFu); al[j]=(short)(la[j]>>16); }
      #pragma unroll
      for (int g=0; g<4; g++){
        bf16x8 bh = *(const bf16x8*)(Whi + (g*16+lrow)*WSTR + 192 + kb);
        bf16x8 bl = *(const bf16x8*)(Wlo + (g*16+lrow)*WSTR + 192 + kb);
        acc[g] = __builtin_amdgcn_mfma_f32_16x16x32_bf16(ah, bh, acc[g], 0,0,0);
        acc[g] = __builtin_amdgcn_mfma_f32_16x16x32_bf16(ah, bl, acc[g], 0,0,0);
        acc[g] = __builtin_amdgcn_mfma_f32_16x16x32_bf16(al, bh, acc[g], 0,0,0);
      }
    }
    // ---- cell (c in registers), h/eo writes ----
    #pragma unroll
    for (int r=0; r<4; r++){
      int brow = mrow + kblk*4 + r;
      float gi = acc[0][r] + bg4[0];
      float gf = acc[1][r] + bg4[1];
      float gg = acc[2][r] + bg4[2];
      float go = acc[3][r] + bg4[3];
      float cn = sigm(gf)*c_reg[r] + sigm(gi)*tanhf(gg);
      float hn = sigm(go)*tanhf(cn);
      c_reg[r] = cn;
      u32 hp = packsplit(hn);
      hout[(size_t)brow*H_ + u0 + lrow] = hp;
      eo32[((size_t)brow*T_ + t)*512 + dir*H_ + u0 + lrow] = hp;  // normal store: seed L2/L3
    }
    if (s == T_-1) break;
    __syncthreads();
    if (tid == 0)
      __hip_atomic_fetch_add(&gbar[s], 1, __ATOMIC_RELEASE, __HIP_MEMORY_SCOPE_AGENT);
  }
}

// ---- persistent decoder (r13 structure; throttled polls + h-part GEMM prefetch) ----
__global__ __launch_bounds__(512) void dec_scan(
    const u32* __restrict__ eo32,
    const u16* __restrict__ Wet_hi, const u16* __restrict__ Wet_lo,
    const float* __restrict__ W_ih, const float* __restrict__ b_ih,
    const float* __restrict__ W_ic, const float* __restrict__ b_ic,
    const float* __restrict__ x, float* __restrict__ ep,
    const float* __restrict__ Wd, const float* __restrict__ v,
    const float* __restrict__ Wo, const float* __restrict__ bo,
    const u16* __restrict__ W_hi, const u16* __restrict__ W_lo,
    const float* __restrict__ b_d, const float* __restrict__ Wx_d,
    float* __restrict__ hdp, float* __restrict__ cd,
    u32* __restrict__ Ad32, float* __restrict__ py,
    float* __restrict__ out, int* __restrict__ cntA, int* __restrict__ cntB)
{
  __shared__ float sh_h[256], sh_hwd[64], sh_v[64], sh_sc[256], sh_w[256];
  __shared__ float red8[8][64];
  __shared__ float sh_red[4], sh_red2[4];
  __shared__ float redc[8][512];
  __shared__ float gl[8][16][16];
  __shared__ float em_s[512];
  __shared__ u32 eoL[CT*512];          // eo t<CT cache (114 KB)
  const int b = blockIdx.x, tid = threadIdx.x;
  const int wave = tid >> 6, lane = tid & 63;
  const int bx = ((b & 7) << 1) | ((b >> 3) & 1);   // XCD-aligned unit tile
  const int by = b >> 4;                            // row-group
  const int cr = tid >> 4, cu = tid & 15;  // cell role (tid<256)
  float c_reg = 0.f;
  float bg0=0,bg1=0,bg2=0,bg3=0, w00=0,w01=0,w02=0,w03=0;
  if (tid < 256){
    int uu = bx*16 + cu;
    bg0 = b_d[uu];       bg1 = b_d[256+uu];
    bg2 = b_d[512+uu];   bg3 = b_d[768+uu];
    w00 = Wx_d[uu];      w01 = Wx_d[256+uu];
    w02 = Wx_d[512+uu];  w03 = Wx_d[768+uu];
  }
  // ================= prologue (block-local) =================
  {   // stage eo t<CT into LDS (coalesced u32x4)
    const u32* src = eo32 + (size_t)b*T_*512;
    for (int i = tid; i < CT*512/4; i += 512)
      ((u32x4*)eoL)[i] = *(const u32x4*)(src + (size_t)i*4);
  }
  {
    const int lrow = lane & 15, kblk = lane >> 4, koff = kblk*8;
    // ep rows: [256t x 64] = eo[b] @ We^T (split MFMA); 8 waves x 2 M-tiles
    #pragma unroll
    for (int mi=0; mi<2; mi++){
      int mt = wave*2 + mi;
      f32x4 acc[4] = {};
      for (int ks=0; ks<16; ks++){
        int kb = ks*32 + koff;
        u32x8 ld = *(const u32x8*)(eo32 + ((size_t)b*T_ + mt*16 + lrow)*512 + kb);
        bf16x8 ah, al;
        #pragma unroll
        for (int j=0;j<8;j++){ ah[j]=(short)(ld[j]&0xFFFFu); al[j]=(short)(ld[j]>>16); }
        #pragma unroll
        for (int nf=0; nf<4; nf++){
          bf16x8 bh = *(const bf16x8*)(Wet_hi + (size_t)(nf*16+lrow)*512 + kb);
          bf16x8 bl = *(const bf16x8*)(Wet_lo + (size_t)(nf*16+lrow)*512 + kb);
          acc[nf] = __builtin_amdgcn_mfma_f32_16x16x32_bf16(ah, bh, acc[nf], 0,0,0);
          acc[nf] = __builtin_amdgcn_mfma_f32_16x16x32_bf16(ah, bl, acc[nf], 0,0,0);
          acc[nf] = __builtin_amdgcn_mfma_f32_16x16x32_bf16(al, bh, acc[nf], 0,0,0);
        }
      }
      #pragma unroll
      for (int nf=0; nf<4; nf++)
        #pragma unroll
        for (int r=0; r<4; r++)
          ep[((size_t)b*T_ + mt*16 + kblk*4 + r)*64 + nf*16 + lrow] = acc[nf][r];
    }
  }
  {   // enc-mean of own row
    float cacc[8] = {};
    const u32* eo = eo32 + (size_t)b*T_*512 + lane*8;
    #pragma unroll 8
    for (int tt=0; tt<32; tt++){
      int t = wave*32 + tt;
      u32x4 e0 = *(const u32x4*)(eo + (size_t)t*512);
      u32x4 e1 = *(const u32x4*)(eo + (size_t)t*512 + 4);
      #pragma unroll
      for (int j=0;j<4;j++){ cacc[j] += unpack2f(e0[j]); cacc[4+j] += unpack2f(e1[j]); }
    }
    #pragma unroll
    for (int j=0;j<8;j++) redc[wave][lane*8+j] = cacc[j];
    __syncthreads();
    if (tid < 256){
      float s0=0.f, s1=0.f;
      #pragma unroll
      for (int q=0;q<8;q++){ s0 += redc[q][tid]; s1 += redc[q][256+tid]; }
      em_s[tid] = s0*(1.f/T_); em_s[256+tid] = s1*(1.f/T_);
    }
    __syncthreads();
  }
  if (tid < 256){  // dec_h / dec_c (GEMV + tanh)
    float ah = b_ih[tid], ac = b_ic[tid];
    for (int k=0;k<512;k++){
      float e = em_s[k];
      ah += e*W_ih[(size_t)k*256 + tid];
      ac += e*W_ic[(size_t)k*256 + tid];
    }
    float h0 = tanhf(ah), c0 = tanhf(ac);
    sh_h[tid] = h0;
    hdp[(size_t)b*H_ + tid] = h0;                       // parity 0
    Ad32[(size_t)b*ADLD + 512 + tid] = packsplit(h0);   // h slot 0
    cd[(size_t)b*H_ + tid] = c0;
  }
  if (tid == 0){
    size_t xb = ((size_t)b*T_ + 255)*F_;
    py[b] = (x[xb] + x[xb+2])*0.5f;
  }
  if (tid >= 448) sh_v[tid-448] = v[tid-448];
  __syncthreads();
  // ================= main loop =================
  for (int s=0; s<=HOR_; s++){
    if (s > 0){
      cnt_wait<16>(cntB + (size_t)((s-1)*16 + by)*FPAD, 16, tid);
      if (tid < 256) sh_h[tid] = hdp[(size_t)(s&1)*B_*H_ + (size_t)b*H_ + tid];
      __syncthreads();
      if (tid < 256){                    // head: y_{s-1}, py
        float p = sh_h[tid] * Wo[tid];
        p = wred_sum(p);
        if ((tid & 63) == 0) sh_red[tid>>6] = p;
      }
      __syncthreads();
      if (tid == 0){
        float y = sh_red[0]+sh_red[1]+sh_red[2]+sh_red[3] + bo[0];
        out[b*HOR_ + (s-1)] = y;
        py[b] = y;
      }
    }
    if (s == HOR_) break;
    {   // hWd
      float ssum = 0.f;
      for (int j=wave*32; j<wave*32+32; j++) ssum += sh_h[j]*Wd[(size_t)j*A_ + lane];
      red8[wave][lane] = ssum;
      __syncthreads();
      if (tid < 64){
        float a = 0.f;
        #pragma unroll
        for (int q=0;q<8;q++) a += red8[q][tid];
        sh_hwd[tid] = a;
      }
    }
    __syncthreads();
    {   // scores: 2 lanes per t
      int t = tid >> 1, aa = tid & 1;
      const float4* ep4 = (const float4*)(ep + ((size_t)(b*T_+t))*A_ + aa*32);
      float partial = 0.f;
      #pragma unroll
      for (int q=0;q<8;q++){
        float4 e4 = ep4[q];
        int a0 = aa*32 + q*4;
        partial += tanhf(e4.x + sh_hwd[a0+0]) * sh_v[a0+0];
        partial += tanhf(e4.y + sh_hwd[a0+1]) * sh_v[a0+1];
        partial += tanhf(e4.z + sh_hwd[a0+2]) * sh_v[a0+2];
        partial += tanhf(e4.w + sh_hwd[a0+3]) * sh_v[a0+3];
      }
      partial += __shfl_xor(partial, 1);
      if (aa == 0) sh_sc[t] = partial;
    }
    __syncthreads();
    if (tid < 256){                      // softmax over T
      float sc = sh_sc[tid];
      float m = wred_max(sc);
      if ((tid&63)==0) sh_red[tid>>6] = m;
      __syncthreads();
      m = fmaxf(fmaxf(sh_red[0],sh_red[1]), fmaxf(sh_red[2],sh_red[3]));
      float e = expf(sc - m);
      float su = wred_sum(e);
      if ((tid&63)==0) sh_red2[tid>>6] = su;
      __syncthreads();
      su = (sh_red2[0]+sh_red2[1])+(sh_red2[2]+sh_red2[3]);
      sh_w[tid] = e / su;
    } else { __syncthreads(); __syncthreads(); }
    __syncthreads();
    {   // context: wave w owns t in [w*32,+32); t<CT from LDS, else global
      float cacc[8] = {};
      const int t0 = wave*32, t1 = t0 + 32;
      const int tL = (t1 < CT) ? t1 : CT;
      for (int t=t0; t<tL; ++t){
        float wgt = sh_w[t];
        const u32* p = eoL + t*512 + lane*8;
        u32x4 e0 = *(const u32x4*)p;
        u32x4 e1 = *(const u32x4*)(p + 4);
        #pragma unroll
        for (int j=0;j<4;j++){
          cacc[j]   += wgt * unpack2f(e0[j]);
          cacc[4+j] += wgt * unpack2f(e1[j]);
        }
      }
      const u32* eo = eo32 + (size_t)b*T_*512 + lane*8;
      const int tG = (t0 > CT) ? t0 : CT;
      #pragma unroll 8
      for (int t=tG; t<t1; ++t){
        float wgt = sh_w[t];
        u32x4 e0 = *(const u32x4*)(eo + (size_t)t*512);
        u32x4 e1 = *(const u32x4*)(eo + (size_t)t*512 + 4);
        #pragma unroll
        for (int j=0;j<4;j++){
          cacc[j]   += wgt * unpack2f(e0[j]);
          cacc[4+j] += wgt * unpack2f(e1[j]);
        }
      }
      #pragma unroll
      for (int j=0;j<8;j++) redc[wave][lane*8+j] = cacc[j];
    }
    __syncthreads();
    if (tid < 256){
      float c0 = 0.f, c1 = 0.f;
      #pragma unroll
      for (int q=0;q<8;q++){ c0 += redc[q][tid]; c1 += redc[q][256+tid]; }
      Ad32[(size_t)b*ADLD + tid]       = packsplit(c0);
      Ad32[(size_t)b*ADLD + 256 + tid] = packsplit(c1);
    }
    __syncthreads();                     // drain ctx/py/out stores
    if (tid == 0)
      cnt_signal(cntA + (size_t)(s*16 + by)*FPAD);
    // ---- phase B ----
    const int par = s & 1;
    const int gB = wave & 3, khB = wave >> 2;
    const int r16 = lane & 15, kb4 = lane >> 4;
    f32x4 accB = {0.f,0.f,0.f,0.f};
    const u32* arB = Ad32 + (size_t)(by*16 + r16)*ADLD;
    const u16* WHB = W_hi + (size_t)(gB*256 + bx*16 + r16)*768;
    const u16* WLB = W_lo + (size_t)(gB*256 + bx*16 + r16)*768;
    // h-part prefetch (K 512..767 depends only on h(s), visible since
    // top-of-step cntB acquire) -> overlap with the cntA barrier. s=0
    // excluded: other blocks' prologue h-writes are only covered by cntA.
    const bool pre = (khB == 1) && (s > 0);
    if (pre){
      for (int ks=16; ks<24; ks++){
        int kb = ks*32 + kb4*8;
        int kp = kb + (par<<8);
        u32x8 ld = *(const u32x8*)(arB + kp);
        bf16x8 ah, al;
        #pragma unroll
        for (int j=0;j<8;j++){ ah[j]=(short)(ld[j]&0xFFFFu); al[j]=(short)(ld[j]>>16); }
        bf16x8 bh = *(const bf16x8*)(WHB + kb);
        bf16x8 bl = *(const bf16x8*)(WLB + kb);
        accB = __builtin_amdgcn_mfma_f32_16x16x32_bf16(ah, bh, accB, 0,0,0);
        accB = __builtin_amdgcn_mfma_f32_16x16x32_bf16(ah, bl, accB, 0,0,0);
        accB = __builtin_amdgcn_mfma_f32_16x16x32_bf16(al, bh, accB, 0,0,0);
      }
    }
    cnt_wait<16>(cntA + (size_t)(s*16 + by)*FPAD, 16, tid);
    if (s == 0 && tid < 256)
      c_reg = cd[(size_t)(by*16 + cr)*H_ + bx*16 + cu];
    {
      const int ksEnd = khB ? (pre ? 16 : 24) : 12;
      for (int ks=khB*12; ks<ksEnd; ks++){
        int kb = ks*32 + kb4*8;
        int kp = (kb < 512) ? kb : (kb + (par<<8));   // parity slot for h
        u32x8 ld = *(const u32x8*)(arB + kp);
        bf16x8 ah, al;
        #pragma unroll
        for (int j=0;j<8;j++){ ah[j]=(short)(ld[j]&0xFFFFu); al[j]=(short)(ld[j]>>16); }
        bf16x8 bh = *(const bf16x8*)(WHB + kb);
        bf16x8 bl = *(const bf16x8*)(WLB + kb);
        accB = __builtin_amdgcn_mfma_f32_16x16x32_bf16(ah, bh, accB, 0,0,0);
        accB = __builtin_amdgcn_mfma_f32_16x16x32_bf16(ah, bl, accB, 0,0,0);
        accB = __builtin_amdgcn_mfma_f32_16x16x32_bf16(al, bh, accB, 0,0,0);
      }
      #pragma unroll
      for (int vv=0; vv<4; vv++) gl[wave][kb4*4+vv][r16] = accB[vv];
    }
    __syncthreads();
    if (tid < 256){                      // cell: thread (cr,cu), c in register
      float pyr = py[by*16 + cr];
      float gi = gl[0][cr][cu] + gl[4][cr][cu] + bg0 + pyr*w00;
      float gf = gl[1][cr][cu] + gl[5][cr][cu] + bg1 + pyr*w01;
      float gg = gl[2][cr][cu] + gl[6][cr][cu] + bg2 + pyr*w02;
      float go = gl[3][cr][cu] + gl[7][cr][cu] + bg3 + pyr*w03;
      float cn = sigm(gf)*c_reg + sigm(gi)*tanhf(gg);
      float hn = sigm(go)*tanhf(cn);
      c_reg = cn;
      size_t ridx = (size_t)(by*16+cr)*H_ + bx*16+cu;
      hdp[(size_t)((s+1)&1)*B_*H_ + ridx] = hn;
      Ad32[(size_t)(by*16+cr)*ADLD + 512 + (((s+1)&1)<<8) + bx*16+cu] = packsplit(hn);
    }
    __syncthreads();                     // drain h stores
    if (tid == 0)
      cnt_signal(cntB + (size_t)(s*16 + by)*FPAD);
  }
}

extern "C" void kernel_launch(void* const* d_in, const int* in_sizes, int n_in,
                              void* d_out, int out_size, void* d_ws, size_t ws_size,
                              hipStream_t stream)
{
  const float* x    = (const float*)d_in[0];
  const float* W_sp = (const float*)d_in[1];
  const float* b_sp = (const float*)d_in[2];
  const float* Wx_ef= (const float*)d_in[3];
  const float* Wh_ef= (const float*)d_in[4];
  const float* b_ef = (const float*)d_in[5];
  const float* Wx_eb= (const float*)d_in[6];
  const float* Wh_eb= (const float*)d_in[7];
  const float* b_eb = (const float*)d_in[8];
  const float* We   = (const float*)d_in[9];
  const float* Wd   = (const float*)d_in[10];
  const float* v    = (const float*)d_in[11];
  const float* Wx_d = (const float*)d_in[12];
  const float* Wh_d = (const float*)d_in[13];
  const float* b_d  = (const float*)d_in[14];
  const float* W_ih = (const float*)d_in[15];
  const float* b_ih = (const float*)d_in[16];
  const float* W_ic = (const float*)d_in[17];
  const float* b_ic = (const float*)d_in[18];
  const float* Wo   = (const float*)d_in[19];
  const float* bo   = (const float*)d_in[20];
  float* out = (float*)d_out;

  char* base = (char*)d_ws;
  auto alloc = [&](size_t bytes)->char*{
    char* p = base; base += (bytes + 255) & ~(size_t)255; return p;
  };
  u16* Wenc_hi = (u16*)alloc((size_t)2*1024*448*2);
  u16* Wenc_lo = (u16*)alloc((size_t)2*1024*448*2);
  u16* Wdec_hi = (u16*)alloc((size_t)1024*768*2);
  u16* Wdec_lo = (u16*)alloc((size_t)1024*768*2);
  u16* Wet_hi  = (u16*)alloc((size_t)64*512*2);
  u16* Wet_lo  = (u16*)alloc((size_t)64*512*2);
  u32* hsp32   = (u32*)alloc((size_t)T_*B_*DSP_*4);
  u32* hbuf    = (u32*)alloc((size_t)2*2*B_*H_*4);   // [parity][dir][b][u]
  u32* eo32    = (u32*)alloc((size_t)B_*T_*512*4);
  float* ep    = (float*)alloc((size_t)B_*T_*64*4);
  float* cd    = (float*)alloc((size_t)B_*H_*4);
  float* hdp   = (float*)alloc((size_t)2*B_*H_*4);   // parity h (fp32)
  u32* Ad32    = (u32*)alloc((size_t)B_*ADLD*4);
  float* pyb   = (float*)alloc((size_t)B_*4);
  int* bar     = (int*)alloc((size_t)8*T_*4);        // enc counters (r8)
  int* cntA    = (int*)alloc((size_t)HOR_*16*FPAD*4);
  int* cntB    = (int*)alloc((size_t)HOR_*16*FPAD*4);
  if ((size_t)(base - (char*)d_ws) > ws_size) return;

  // one-time weight conversions
  conv_w<<<dim3(1792),256,0,stream>>>(Wx_ef, Wh_ef, Wenc_hi, Wenc_lo, DSP_, 448, 1024);
  conv_w<<<dim3(1792),256,0,stream>>>(Wx_eb, Wh_eb, Wenc_hi+458752, Wenc_lo+458752, DSP_, 448, 1024);
  conv_w<<<dim3(3072),256,0,stream>>>(Wx_d+1024, Wh_d, Wdec_hi, Wdec_lo, 512, 768, 1024);
  conv_w<<<dim3(128),256,0,stream>>>(We, We, Wet_hi, Wet_lo, 512, 512, 64);

  spatial_proj<<<dim3(256),192,0,stream>>>(x, W_sp, b_sp, hsp32);

  hipMemsetAsync(hbuf, 0, (size_t)2*B_*H_*4, stream);          // parity-0 h = 0
  hipMemsetAsync(bar, 0, (size_t)8*T_*4, stream);              // enc counters
  hipMemsetAsync(cntA, 0, (size_t)HOR_*16*FPAD*4, stream);     // dec counters
  hipMemsetAsync(cntB, 0, (size_t)HOR_*16*FPAD*4, stream);

  enc_scan<<<dim3(ENC_NBLK), dim3(256), 2*4*16*WSTR*2, stream>>>(
      hsp32, Wenc_hi, Wenc_lo, b_ef, b_eb, hbuf, eo32, bar);

  dec_scan<<<dim3(256),512,0,stream>>>(
      eo32, Wet_hi, Wet_lo, W_ih, b_ih, W_ic, b_ic, x, ep,
      Wd, v, Wo, bo, Wdec_hi, Wdec_lo, b_d, Wx_d,
      hdp, cd, Ad32, pyb, out, cntA, cntB);
}

// Round 16
// 5433.801 us; speedup vs baseline: 1.0639x; 1.0041x over previous
//
#include <hip/hip_runtime.h>
#include <cmath>

#define B_ 256
#define T_ 256
#define F_ 40
#define H_ 256
#define A_ 64
#define HOR_ 60
#define DSP_ 192
#define ENC_NBLK 128
#define WSTR 456      // LDS weight row stride in u16 (448 + pad)
#define FPAD 32       // counter stride in ints (128 B -> own cacheline)
#define ADLD 1024     // Ad32 row stride: ctx(512) | h_even(256) | h_odd(256)
#define CT 56         // eo t-rows cached in LDS per decoder block

typedef unsigned short u16;
typedef unsigned int u32;
typedef __attribute__((ext_vector_type(8))) short bf16x8;
typedef __attribute__((ext_vector_type(4))) float f32x4;
typedef __attribute__((ext_vector_type(8))) u32 u32x8;
typedef __attribute__((ext_vector_type(4))) u32 u32x4;

__device__ __forceinline__ float sigm(float x){ return 1.f/(1.f+expf(-x)); }

__device__ __forceinline__ u16 f2bf(float x){
  u32 u = __float_as_uint(x);
  u32 r = (u + 0x7FFFu + ((u>>16)&1u)) >> 16;
  return (u16)r;
}
__device__ __forceinline__ float bf2f(u16 h){ return __uint_as_float(((u32)h)<<16); }
__device__ __forceinline__ u32 packsplit(float x){
  u16 hi = f2bf(x);
  u16 lo = f2bf(x - bf2f(hi));
  return (u32)hi | ((u32)lo<<16);
}
__device__ __forceinline__ float unpack2f(u32 v){
  return __uint_as_float(v<<16) + __uint_as_float(v & 0xFFFF0000u);
}

__device__ __forceinline__ float wred_sum(float v){
  #pragma unroll
  for (int o=32;o>0;o>>=1) v += __shfl_xor(v,o);
  return v;
}
__device__ __forceinline__ float wred_max(float v){
  #pragma unroll
  for (int o=32;o>0;o>>=1) v = fmaxf(v,__shfl_xor(v,o));
  return v;
}

// PROVEN barrier primitive, now 4-way parallelized: each barrier is FOUR
// padded counters of 4 arrivals (q = idx>>2). Arrival: RELEASE fetch_add on
// the block's own counter line (4 short convoys run in parallel instead of
// one 16-deep convoy). Wait: lanes 0-3 of wave 0 each ACQUIRE-poll one
// counter (every poll invalidates, exactly like the proven single-lane
// pattern; no relaxed polls) + syncthreads.
__device__ __forceinline__ void cnt_signal(int* c){
  __hip_atomic_fetch_add(c, 1, __ATOMIC_RELEASE, __HIP_MEMORY_SCOPE_AGENT);
}
template<int SLP>
__device__ __forceinline__ void cnt_wait4(const int* base, int need, int tid){
  if (tid < 4){
    const int* c = base + (size_t)tid*FPAD;
    while (__hip_atomic_load(c, __ATOMIC_ACQUIRE, __HIP_MEMORY_SCOPE_AGENT) < need)
      __builtin_amdgcn_s_sleep(SLP);
  }
  __syncthreads();
}

// ---- weight conversion: dst[n][k] (hi/lo bf16) = src[k][n], src = [Wx ; Wh] ----
__global__ void conv_w(const float* __restrict__ Wx, const float* __restrict__ Wh,
                       u16* __restrict__ hi, u16* __restrict__ lo,
                       int KX, int Ktot, int N){
  int idx = blockIdx.x*256 + threadIdx.x;
  if (idx >= N*Ktot) return;
  int n = idx / Ktot, k = idx - n*Ktot;
  float w = (k < KX) ? Wx[(size_t)k*N + n] : Wh[(size_t)(k-KX)*N + n];
  u16 h = f2bf(w);
  hi[idx] = h;
  lo[idx] = f2bf(w - bf2f(h));
}

// ---- spatial projection: hsp32[t][b][192] packed = x[b][t][:40] @ W_sp + b_sp ----
__global__ __launch_bounds__(192) void spatial_proj(
    const float* __restrict__ x, const float* __restrict__ W, const float* __restrict__ bsp,
    u32* __restrict__ hsp32){
  __shared__ float Ws[40][192];
  __shared__ float xr[40];
  int t = blockIdx.x, tid = threadIdx.x;
  for (int i = tid; i < 40*192; i += 192){ int k = i/192, c = i-k*192; Ws[k][c] = W[i]; }
  float bb = bsp[tid];
  __syncthreads();
  for (int b=0; b<B_; b++){
    if (tid < 40) xr[tid] = x[((size_t)b*T_ + t)*F_ + tid];
    __syncthreads();
    float acc = bb;
    #pragma unroll
    for (int k=0;k<40;k++) acc += xr[k]*Ws[k][tid];
    hsp32[((size_t)t*B_ + b)*DSP_ + tid] = packsplit(acc);
    __syncthreads();
  }
}

// ---- persistent bidirectional encoder scan (r8 structure; 4-way split barrier) ----
__global__ __launch_bounds__(256) void enc_scan(
    const u32* __restrict__ hsp32,
    const u16* __restrict__ W_hi, const u16* __restrict__ W_lo,
    const float* __restrict__ b_ef, const float* __restrict__ b_eb,
    u32* __restrict__ hbuf, u32* __restrict__ eo32, int* __restrict__ bar)
{
  extern __shared__ u16 smem[];
  u16* Whi = smem;                    // [4 gates][16 units][WSTR]
  u16* Wlo = smem + 4*16*WSTR;
  const int bid = blockIdx.x;
  const int grp = bid & 7;            // dir*4 + mtile
  const int nt  = bid >> 3;
  const int dir = grp >> 2;
  const int m0  = (grp & 3) * 64;
  const int u0  = nt * 16;
  const int tid = threadIdx.x;
  const int wave = tid >> 6, lane = tid & 63;
  const int lrow = lane & 15, kblk = lane >> 4;
  const int koff = kblk * 8;
  {
    const size_t wbase = ((size_t)dir*1024 + u0) * 448;
    for (int idx = tid; idx < 4*16*448; idx += 256){
      int g = idx / (16*448);
      int r = idx - g*(16*448);
      int j = r / 448;
      int k = r - j*448;
      size_t go = wbase + ((size_t)g*256 + j)*448 + k;
      Whi[(g*16 + j)*WSTR + k] = W_hi[go];
      Wlo[(g*16 + j)*WSTR + k] = W_lo[go];
    }
  }
  const float* bias = dir ? b_eb : b_ef;
  float bg4[4];
  #pragma unroll
  for (int g=0; g<4; g++) bg4[g] = bias[g*H_ + u0 + lrow];
  __syncthreads();

  const int mrow = m0 + wave*16;
  const int arow = mrow + lrow;
  u32* hP0 = hbuf + (size_t)dir*(B_*H_);
  u32* hP1 = hbuf + (size_t)(2+dir)*(B_*H_);
  float c_reg[4] = {0.f,0.f,0.f,0.f};

  for (int s=0; s<T_; s++){
    const int t = dir ? (T_-1-s) : s;
    f32x4 acc[4] = {};
    // ---- x part (k 0..191): independent of h -> before barrier ----
    const u32* abase = hsp32 + ((size_t)t*B_ + arow)*DSP_;
    #pragma unroll
    for (int ks=0; ks<6; ks++){
      int kb = ks*32 + koff;
      u32x8 la = *(const u32x8*)(abase + kb);
      bf16x8 ah, al;
      #pragma unroll
      for (int j=0;j<8;j++){ ah[j]=(short)(la[j]&0xFFFFu); al[j]=(short)(la[j]>>16); }
      #pragma unroll
      for (int g=0; g<4; g++){
        bf16x8 bh = *(const bf16x8*)(Whi + (g*16+lrow)*WSTR + kb);
        bf16x8 bl = *(const bf16x8*)(Wlo + (g*16+lrow)*WSTR + kb);
        acc[g] = __builtin_amdgcn_mfma_f32_16x16x32_bf16(ah, bh, acc[g], 0,0,0);
        acc[g] = __builtin_amdgcn_mfma_f32_16x16x32_bf16(ah, bl, acc[g], 0,0,0);
        acc[g] = __builtin_amdgcn_mfma_f32_16x16x32_bf16(al, bh, acc[g], 0,0,0);
      }
    }
    // ---- wait for group's h(s-1): 4 parallel counters of 4 ----
    if (s > 0)
      cnt_wait4<8>(bar + (size_t)((grp*T_ + (s-1))*4)*FPAD, 4, tid);
    const u32* hin = (s & 1) ? hP1 : hP0;
    u32* hout      = (s & 1) ? hP0 : hP1;
    // ---- h part (k 192..447) ----
    const u32* hbase = hin + (size_t)arow*H_;
    #pragma unroll
    for (int ks=0; ks<8; ks++){
      int kb = ks*32 + koff;
      u32x8 la = *(const u32x8*)(hbase + kb);
      bf16x8 ah, al;
      #pragma unroll
      for (int j=0;j<8;j++){ ah[j]=(short)(la[j]&0xFFFFu); al[j]=(short)(la[j]>>16); }
      #pragma unroll
      for (int g=0; g<4; g++){
        bf16x8 bh = *(const bf16x8*)(Whi + (g*16+lrow)*WSTR + 192 + kb);
        bf16x8 bl = *(const bf16x8*)(Wlo + (g*16+lrow)*WSTR + 192 + kb);
        acc[g] = __builtin_amdgcn_mfma_f32_16x16x32_bf16(ah, bh, acc[g], 0,0,0);
        acc[g] = __builtin_amdgcn_mfma_f32_16x16x32_bf16(ah, bl, acc[g], 0,0,0);
        acc[g] = __builtin_amdgcn_mfma_f32_16x16x32_bf16(al, bh, acc[g], 0,0,0);
      }
    }
    // ---- cell (c in registers), h/eo writes ----
    #pragma unroll
    for (int r=0; r<4; r++){
      int brow = mrow + kblk*4 + r;
      float gi = acc[0][r] + bg4[0];
      float gf = acc[1][r] + bg4[1];
      float gg = acc[2][r] + bg4[2];
      float go = acc[3][r] + bg4[3];
      float cn = sigm(gf)*c_reg[r] + sigm(gi)*tanhf(gg);
      float hn = sigm(go)*tanhf(cn);
      c_reg[r] = cn;
      u32 hp = packsplit(hn);
      hout[(size_t)brow*H_ + u0 + lrow] = hp;
      eo32[((size_t)brow*T_ + t)*512 + dir*H_ + u0 + lrow] = hp;  // normal store: seed L2/L3
    }
    if (s == T_-1) break;
    __syncthreads();
    if (tid == 0)
      cnt_signal(bar + (size_t)((grp*T_ + s)*4 + (nt>>2))*FPAD);
  }
}

// ---- persistent decoder (r15 structure; 4-way barriers + balanced GEMM split) ----
__global__ __launch_bounds__(512) void dec_scan(
    const u32* __restrict__ eo32,
    const u16* __restrict__ Wet_hi, const u16* __restrict__ Wet_lo,
    const float* __restrict__ W_ih, const float* __restrict__ b_ih,
    const float* __restrict__ W_ic, const float* __restrict__ b_ic,
    const float* __restrict__ x, float* __restrict__ ep,
    const float* __restrict__ Wd, const float* __restrict__ v,
    const float* __restrict__ Wo, const float* __restrict__ bo,
    const u16* __restrict__ W_hi, const u16* __restrict__ W_lo,
    const float* __restrict__ b_d, const float* __restrict__ Wx_d,
    float* __restrict__ hdp, float* __restrict__ cd,
    u32* __restrict__ Ad32, float* __restrict__ py,
    float* __restrict__ out, int* __restrict__ cntA, int* __restrict__ cntB)
{
  __shared__ float sh_h[256], sh_hwd[64], sh_v[64], sh_sc[256], sh_w[256];
  __shared__ float red8[8][64];
  __shared__ float sh_red[4], sh_red2[4];
  __shared__ float redc[8][512];
  __shared__ float gl[8][16][16];
  __shared__ float em_s[512];
  __shared__ u32 eoL[CT*512];          // eo t<CT cache (114 KB)
  const int b = blockIdx.x, tid = threadIdx.x;
  const int wave = tid >> 6, lane = tid & 63;
  const int bx = ((b & 7) << 1) | ((b >> 3) & 1);   // XCD-aligned unit tile
  const int by = b >> 4;                            // row-group
  const int cr = tid >> 4, cu = tid & 15;  // cell role (tid<256)
  float c_reg = 0.f;
  float bg0=0,bg1=0,bg2=0,bg3=0, w00=0,w01=0,w02=0,w03=0;
  if (tid < 256){
    int uu = bx*16 + cu;
    bg0 = b_d[uu];       bg1 = b_d[256+uu];
    bg2 = b_d[512+uu];   bg3 = b_d[768+uu];
    w00 = Wx_d[uu];      w01 = Wx_d[256+uu];
    w02 = Wx_d[512+uu];  w03 = Wx_d[768+uu];
  }
  // ================= prologue (block-local) =================
  {   // stage eo t<CT into LDS (coalesced u32x4)
    const u32* src = eo32 + (size_t)b*T_*512;
    for (int i = tid; i < CT*512/4; i += 512)
      ((u32x4*)eoL)[i] = *(const u32x4*)(src + (size_t)i*4);
  }
  {
    const int lrow = lane & 15, kblk = lane >> 4, koff = kblk*8;
    // ep rows: [256t x 64] = eo[b] @ We^T (split MFMA); 8 waves x 2 M-tiles
    #pragma unroll
    for (int mi=0; mi<2; mi++){
      int mt = wave*2 + mi;
      f32x4 acc[4] = {};
      for (int ks=0; ks<16; ks++){
        int kb = ks*32 + koff;
        u32x8 ld = *(const u32x8*)(eo32 + ((size_t)b*T_ + mt*16 + lrow)*512 + kb);
        bf16x8 ah, al;
        #pragma unroll
        for (int j=0;j<8;j++){ ah[j]=(short)(ld[j]&0xFFFFu); al[j]=(short)(ld[j]>>16); }
        #pragma unroll
        for (int nf=0; nf<4; nf++){
          bf16x8 bh = *(const bf16x8*)(Wet_hi + (size_t)(nf*16+lrow)*512 + kb);
          bf16x8 bl = *(const bf16x8*)(Wet_lo + (size_t)(nf*16+lrow)*512 + kb);
          acc[nf] = __builtin_amdgcn_mfma_f32_16x16x32_bf16(ah, bh, acc[nf], 0,0,0);
          acc[nf] = __builtin_amdgcn_mfma_f32_16x16x32_bf16(ah, bl, acc[nf], 0,0,0);
          acc[nf] = __builtin_amdgcn_mfma_f32_16x16x32_bf16(al, bh, acc[nf], 0,0,0);
        }
      }
      #pragma unroll
      for (int nf=0; nf<4; nf++)
        #pragma unroll
        for (int r=0; r<4; r++)
          ep[((size_t)b*T_ + mt*16 + kblk*4 + r)*64 + nf*16 + lrow] = acc[nf][r];
    }
  }
  {   // enc-mean of own row
    float cacc[8] = {};
    const u32* eo = eo32 + (size_t)b*T_*512 + lane*8;
    #pragma unroll 8
    for (int tt=0; tt<32; tt++){
      int t = wave*32 + tt;
      u32x4 e0 = *(const u32x4*)(eo + (size_t)t*512);
      u32x4 e1 = *(const u32x4*)(eo + (size_t)t*512 + 4);
      #pragma unroll
      for (int j=0;j<4;j++){ cacc[j] += unpack2f(e0[j]); cacc[4+j] += unpack2f(e1[j]); }
    }
    #pragma unroll
    for (int j=0;j<8;j++) redc[wave][lane*8+j] = cacc[j];
    __syncthreads();
    if (tid < 256){
      float s0=0.f, s1=0.f;
      #pragma unroll
      for (int q=0;q<8;q++){ s0 += redc[q][tid]; s1 += redc[q][256+tid]; }
      em_s[tid] = s0*(1.f/T_); em_s[256+tid] = s1*(1.f/T_);
    }
    __syncthreads();
  }
  if (tid < 256){  // dec_h / dec_c (GEMV + tanh)
    float ah = b_ih[tid], ac = b_ic[tid];
    for (int k=0;k<512;k++){
      float e = em_s[k];
      ah += e*W_ih[(size_t)k*256 + tid];
      ac += e*W_ic[(size_t)k*256 + tid];
    }
    float h0 = tanhf(ah), c0 = tanhf(ac);
    sh_h[tid] = h0;
    hdp[(size_t)b*H_ + tid] = h0;                       // parity 0
    Ad32[(size_t)b*ADLD + 512 + tid] = packsplit(h0);   // h slot 0
    cd[(size_t)b*H_ + tid] = c0;
  }
  if (tid == 0){
    size_t xb = ((size_t)b*T_ + 255)*F_;
    py[b] = (x[xb] + x[xb+2])*0.5f;
  }
  if (tid >= 448) sh_v[tid-448] = v[tid-448];
  __syncthreads();
  // ================= main loop =================
  for (int s=0; s<=HOR_; s++){
    if (s > 0){
      cnt_wait4<16>(cntB + (size_t)(((s-1)*16 + by)*4)*FPAD, 4, tid);
      if (tid < 256) sh_h[tid] = hdp[(size_t)(s&1)*B_*H_ + (size_t)b*H_ + tid];
      __syncthreads();
      if (tid < 256){                    // head: y_{s-1}, py
        float p = sh_h[tid] * Wo[tid];
        p = wred_sum(p);
        if ((tid & 63) == 0) sh_red[tid>>6] = p;
      }
      __syncthreads();
      if (tid == 0){
        float y = sh_red[0]+sh_red[1]+sh_red[2]+sh_red[3] + bo[0];
        out[b*HOR_ + (s-1)] = y;
        py[b] = y;
      }
    }
    if (s == HOR_) break;
    {   // hWd
      float ssum = 0.f;
      for (int j=wave*32; j<wave*32+32; j++) ssum += sh_h[j]*Wd[(size_t)j*A_ + lane];
      red8[wave][lane] = ssum;
      __syncthreads();
      if (tid < 64){
        float a = 0.f;
        #pragma unroll
        for (int q=0;q<8;q++) a += red8[q][tid];
        sh_hwd[tid] = a;
      }
    }
    __syncthreads();
    {   // scores: 2 lanes per t
      int t = tid >> 1, aa = tid & 1;
      const float4* ep4 = (const float4*)(ep + ((size_t)(b*T_+t))*A_ + aa*32);
      float partial = 0.f;
      #pragma unroll
      for (int q=0;q<8;q++){
        float4 e4 = ep4[q];
        int a0 = aa*32 + q*4;
        partial += tanhf(e4.x + sh_hwd[a0+0]) * sh_v[a0+0];
        partial += tanhf(e4.y + sh_hwd[a0+1]) * sh_v[a0+1];
        partial += tanhf(e4.z + sh_hwd[a0+2]) * sh_v[a0+2];
        partial += tanhf(e4.w + sh_hwd[a0+3]) * sh_v[a0+3];
      }
      partial += __shfl_xor(partial, 1);
      if (aa == 0) sh_sc[t] = partial;
    }
    __syncthreads();
    if (tid < 256){                      // softmax over T
      float sc = sh_sc[tid];
      float m = wred_max(sc);
      if ((tid&63)==0) sh_red[tid>>6] = m;
      __syncthreads();
      m = fmaxf(fmaxf(sh_red[0],sh_red[1]), fmaxf(sh_red[2],sh_red[3]));
      float e = expf(sc - m);
      float su = wred_sum(e);
      if ((tid&63)==0) sh_red2[tid>>6] = su;
      __syncthreads();
      su = (sh_red2[0]+sh_red2[1])+(sh_red2[2]+sh_red2[3]);
      sh_w[tid] = e / su;
    } else { __syncthreads(); __syncthreads(); }
    __syncthreads();
    {   // context: wave w owns t in [w*32,+32); t<CT from LDS, else global
      float cacc[8] = {};
      const int t0 = wave*32, t1 = t0 + 32;
      const int tL = (t1 < CT) ? t1 : CT;
      for (int t=t0; t<tL; ++t){
        float wgt = sh_w[t];
        const u32* p = eoL + t*512 + lane*8;
        u32x4 e0 = *(const u32x4*)p;
        u32x4 e1 = *(const u32x4*)(p + 4);
        #pragma unroll
        for (int j=0;j<4;j++){
          cacc[j]   += wgt * unpack2f(e0[j]);
          cacc[4+j] += wgt * unpack2f(e1[j]);
        }
      }
      const u32* eo = eo32 + (size_t)b*T_*512 + lane*8;
      const int tG = (t0 > CT) ? t0 : CT;
      #pragma unroll 8
      for (int t=tG; t<t1; ++t){
        float wgt = sh_w[t];
        u32x4 e0 = *(const u32x4*)(eo + (size_t)t*512);
        u32x4 e1 = *(const u32x4*)(eo + (size_t)t*512 + 4);
        #pragma unroll
        for (int j=0;j<4;j++){
          cacc[j]   += wgt * unpack2f(e0[j]);
          cacc[4+j] += wgt * unpack2f(e1[j]);
        }
      }
      #pragma unroll
      for (int j=0;j<8;j++) redc[wave][lane*8+j] = cacc[j];
    }
    __syncthreads();
    if (tid < 256){
      float c0 = 0.f, c1 = 0.f;
      #pragma unroll
      for (int q=0;q<8;q++){ c0 += redc[q][tid]; c1 += redc[q][256+tid]; }
      Ad32[(size_t)b*ADLD + tid]       = packsplit(c0);
      Ad32[(size_t)b*ADLD + 256 + tid] = packsplit(c1);
    }
    __syncthreads();                     // drain ctx/py/out stores
    if (tid == 0)
      cnt_signal(cntA + (size_t)((s*16 + (b>>4))*4 + ((b&15)>>2))*FPAD);
    // ---- phase B (balanced K-split: khB0 -> ks 0..8, khB1 -> ks 8..24) ----
    const int par = s & 1;
    const int gB = wave & 3, khB = wave >> 2;
    const int r16 = lane & 15, kb4 = lane >> 4;
    f32x4 accB = {0.f,0.f,0.f,0.f};
    const u32* arB = Ad32 + (size_t)(by*16 + r16)*ADLD;
    const u16* WHB = W_hi + (size_t)(gB*256 + bx*16 + r16)*768;
    const u16* WLB = W_lo + (size_t)(gB*256 + bx*16 + r16)*768;
    // h-part prefetch (K 512..767 depends only on h(s), visible since
    // top-of-step cntB acquire) -> overlap with the cntA barrier. s=0
    // excluded: other blocks' prologue h-writes are only covered by cntA.
    const bool pre = (khB == 1) && (s > 0);
    if (pre){
      for (int ks=16; ks<24; ks++){
        int kb = ks*32 + kb4*8;
        int kp = kb + (par<<8);
        u32x8 ld = *(const u32x8*)(arB + kp);
        bf16x8 ah, al;
        #pragma unroll
        for (int j=0;j<8;j++){ ah[j]=(short)(ld[j]&0xFFFFu); al[j]=(short)(ld[j]>>16); }
        bf16x8 bh = *(const bf16x8*)(WHB + kb);
        bf16x8 bl = *(const bf16x8*)(WLB + kb);
        accB = __builtin_amdgcn_mfma_f32_16x16x32_bf16(ah, bh, accB, 0,0,0);
        accB = __builtin_amdgcn_mfma_f32_16x16x32_bf16(ah, bl, accB, 0,0,0);
        accB = __builtin_amdgcn_mfma_f32_16x16x32_bf16(al, bh, accB, 0,0,0);
      }
    }
    cnt_wait4<16>(cntA + (size_t)((s*16 + by)*4)*FPAD, 4, tid);
    if (s == 0 && tid < 256)
      c_reg = cd[(size_t)(by*16 + cr)*H_ + bx*16 + cu];
    {
      const int ksBeg = khB ? 8 : 0;
      const int ksEnd = khB ? (pre ? 16 : 24) : 8;
      for (int ks=ksBeg; ks<ksEnd; ks++){
        int kb = ks*32 + kb4*8;
        int kp = (kb < 512) ? kb : (kb + (par<<8));   // parity slot for h
        u32x8 ld = *(const u32x8*)(arB + kp);
        bf16x8 ah, al;
        #pragma unroll
        for (int j=0;j<8;j++){ ah[j]=(short)(ld[j]&0xFFFFu); al[j]=(short)(ld[j]>>16); }
        bf16x8 bh = *(const bf16x8*)(WHB + kb);
        bf16x8 bl = *(const bf16x8*)(WLB + kb);
        accB = __builtin_amdgcn_mfma_f32_16x16x32_bf16(ah, bh, accB, 0,0,0);
        accB = __builtin_amdgcn_mfma_f32_16x16x32_bf16(ah, bl, accB, 0,0,0);
        accB = __builtin_amdgcn_mfma_f32_16x16x32_bf16(al, bh, accB, 0,0,0);
      }
      #pragma unroll
      for (int vv=0; vv<4; vv++) gl[wave][kb4*4+vv][r16] = accB[vv];
    }
    __syncthreads();
    if (tid < 256){                      // cell: thread (cr,cu), c in register
      float pyr = py[by*16 + cr];
      float gi = gl[0][cr][cu] + gl[4][cr][cu] + bg0 + pyr*w00;
      float gf = gl[1][cr][cu] + gl[5][cr][cu] + bg1 + pyr*w01;
      float gg = gl[2][cr][cu] + gl[6][cr][cu] + bg2 + pyr*w02;
      float go = gl[3][cr][cu] + gl[7][cr][cu] + bg3 + pyr*w03;
      float cn = sigm(gf)*c_reg + sigm(gi)*tanhf(gg);
      float hn = sigm(go)*tanhf(cn);
      c_reg = cn;
      size_t ridx = (size_t)(by*16+cr)*H_ + bx*16+cu;
      hdp[(size_t)((s+1)&1)*B_*H_ + ridx] = hn;
      Ad32[(size_t)(by*16+cr)*ADLD + 512 + (((s+1)&1)<<8) + bx*16+cu] = packsplit(hn);
    }
    __syncthreads();                     // drain h stores
    if (tid == 0)
      cnt_signal(cntB + (size_t)((s*16 + by)*4 + (bx>>2))*FPAD);
  }
}

extern "C" void kernel_launch(void* const* d_in, const int* in_sizes, int n_in,
                              void* d_out, int out_size, void* d_ws, size_t ws_size,
                              hipStream_t stream)
{
  const float* x    = (const float*)d_in[0];
  const float* W_sp = (const float*)d_in[1];
  const float* b_sp = (const float*)d_in[2];
  const float* Wx_ef= (const float*)d_in[3];
  const float* Wh_ef= (const float*)d_in[4];
  const float* b_ef = (const float*)d_in[5];
  const float* Wx_eb= (const float*)d_in[6];
  const float* Wh_eb= (const float*)d_in[7];
  const float* b_eb = (const float*)d_in[8];
  const float* We   = (const float*)d_in[9];
  const float* Wd   = (const float*)d_in[10];
  const float* v    = (const float*)d_in[11];
  const float* Wx_d = (const float*)d_in[12];
  const float* Wh_d = (const float*)d_in[13];
  const float* b_d  = (const float*)d_in[14];
  const float* W_ih = (const float*)d_in[15];
  const float* b_ih = (const float*)d_in[16];
  const float* W_ic = (const float*)d_in[17];
  const float* b_ic = (const float*)d_in[18];
  const float* Wo   = (const float*)d_in[19];
  const float* bo   = (const float*)d_in[20];
  float* out = (float*)d_out;

  char* base = (char*)d_ws;
  auto alloc = [&](size_t bytes)->char*{
    char* p = base; base += (bytes + 255) & ~(size_t)255; return p;
  };
  u16* Wenc_hi = (u16*)alloc((size_t)2*1024*448*2);
  u16* Wenc_lo = (u16*)alloc((size_t)2*1024*448*2);
  u16* Wdec_hi = (u16*)alloc((size_t)1024*768*2);
  u16* Wdec_lo = (u16*)alloc((size_t)1024*768*2);
  u16* Wet_hi  = (u16*)alloc((size_t)64*512*2);
  u16* Wet_lo  = (u16*)alloc((size_t)64*512*2);
  u32* hsp32   = (u32*)alloc((size_t)T_*B_*DSP_*4);
  u32* hbuf    = (u32*)alloc((size_t)2*2*B_*H_*4);   // [parity][dir][b][u]
  u32* eo32    = (u32*)alloc((size_t)B_*T_*512*4);
  float* ep    = (float*)alloc((size_t)B_*T_*64*4);
  float* cd    = (float*)alloc((size_t)B_*H_*4);
  float* hdp   = (float*)alloc((size_t)2*B_*H_*4);   // parity h (fp32)
  u32* Ad32    = (u32*)alloc((size_t)B_*ADLD*4);
  float* pyb   = (float*)alloc((size_t)B_*4);
  int* bar     = (int*)alloc((size_t)8*T_*4*FPAD*4);     // enc counters (4-way)
  int* cntA    = (int*)alloc((size_t)HOR_*16*4*FPAD*4);  // dec counters (4-way)
  int* cntB    = (int*)alloc((size_t)HOR_*16*4*FPAD*4);
  if ((size_t)(base - (char*)d_ws) > ws_size) return;

  // one-time weight conversions
  conv_w<<<dim3(1792),256,0,stream>>>(Wx_ef, Wh_ef, Wenc_hi, Wenc_lo, DSP_, 448, 1024);
  conv_w<<<dim3(1792),256,0,stream>>>(Wx_eb, Wh_eb, Wenc_hi+458752, Wenc_lo+458752, DSP_, 448, 1024);
  conv_w<<<dim3(3072),256,0,stream>>>(Wx_d+1024, Wh_d, Wdec_hi, Wdec_lo, 512, 768, 1024);
  conv_w<<<dim3(128),256,0,stream>>>(We, We, Wet_hi, Wet_lo, 512, 512, 64);

  spatial_proj<<<dim3(256),192,0,stream>>>(x, W_sp, b_sp, hsp32);

  hipMemsetAsync(hbuf, 0, (size_t)2*B_*H_*4, stream);            // parity-0 h = 0
  hipMemsetAsync(bar, 0, (size_t)8*T_*4*FPAD*4, stream);         // enc counters
  hipMemsetAsync(cntA, 0, (size_t)HOR_*16*4*FPAD*4, stream);     // dec counters
  hipMemsetAsync(cntB, 0, (size_t)HOR_*16*4*FPAD*4, stream);

  enc_scan<<<dim3(ENC_NBLK), dim3(256), 2*4*16*WSTR*2, stream>>>(
      hsp32, Wenc_hi, Wenc_lo, b_ef, b_eb, hbuf, eo32, bar);

  dec_scan<<<dim3(256),512,0,stream>>>(
      eo32, Wet_hi, Wet_lo, W_ih, b_ih, W_ic, b_ic, x, ep,
      Wd, v, Wo, bo, Wdec_hi, Wdec_lo, b_d, Wx_d,
      hdp, cd, Ad32, pyb, out, cntA, cntB);
}